// Round 1
// baseline (1435.258 us; speedup 1.0000x reference)
//
#include <hip/hip_runtime.h>
#include <hip/hip_bf16.h>
#include <cmath>

// ---------------------------------------------------------------------------
// GCN: out = tanh(relu(relu(relu(relu(P(P(P(P(xW1+..)..) .. ))Wf1+bf1)Wf2+bf2
// P = D^-1/2 (A+I) D^-1/2. R6-R12: bucketed CSR + wave-per-node gather-sum,
// producer-prescaled bf16 transport, fused FC head (402.7us).
// R13: edge-parallel aggregation. csr_tmp (bucket-grouped, local-dst in
// payload) is consumed DIRECTLY by the agg: one block per 64-node bucket,
// fp32 accumulation in LDS via ds_add_f32, U=4 flat edge loop (4 gathers in
// flight/lane, perfect load balance). Deletes bsort's node sort, row_ptr,
// csr_src, and all shuffle reductions (~24 ds_swizzle/node). LDS banks
// decorrelated by pad-swizzle: row stride F+8, base offset (ld&7).
// ---------------------------------------------------------------------------

#define NBUCK 1563             // ceil(100000/64): 64-node buckets
#define PREB  391              // ceil(E/4096) edge-phase blocks (16 edges/thread)

typedef __attribute__((ext_vector_type(8))) unsigned short ushort8v;

__device__ __forceinline__ unsigned short f_to_bf(float v) {
    unsigned u = __float_as_uint(v);
    return (unsigned short)((u + 0x7FFF + ((u >> 16) & 1)) >> 16);   // RTN-even
}
__device__ __forceinline__ float bf_to_f(unsigned short v) {
    return __uint_as_float((unsigned)v << 16);
}

__device__ __forceinline__ void unpack8(const ushort8v& u, float* f) {
#pragma unroll
    for (int j = 0; j < 8; j++) f[j] = bf_to_f(u[j]);
}
__device__ __forceinline__ ushort8v pack8(const float* f) {
    ushort8v u;
#pragma unroll
    for (int j = 0; j < 8; j++) u[j] = f_to_bf(f[j]);
    return u;
}

__global__ void zero_kernel(int* p, int n) {
    int i = blockIdx.x * 256 + threadIdx.x;
    if (i < n) p[i] = 0;
}

// bucket histogram only (16 edges/thread, LDS-aggregated)
__global__ __launch_bounds__(256) void hist_kernel(
        const int* __restrict__ dst, int* __restrict__ bucket_cnt, int E) {
    __shared__ int bh[NBUCK];
    const int t = threadIdx.x;
    for (int i = t; i < NBUCK; i += 256) bh[i] = 0;
    __syncthreads();
    const int base = blockIdx.x * 4096;
#pragma unroll
    for (int j = 0; j < 16; j++) {
        int e = base + j * 256 + t;
        if (e < E) atomicAdd(&bh[dst[e] >> 6], 1);
    }
    __syncthreads();
    for (int i = t; i < NBUCK; i += 256)
        if (bh[i]) atomicAdd(&bucket_cnt[i], bh[i]);
}

// exclusive scan of bucket_cnt[NBUCK] -> bucket_start (ro) + bucket_cursor (rw)
// 1024 threads, 2 elements each, Hillis-Steele over 2048 (NBUCK=1563 <= 2048).
__global__ __launch_bounds__(1024) void bucket_scan_kernel(
        const int* __restrict__ bucket_cnt, int* __restrict__ bucket_start,
        int* __restrict__ bucket_cursor, int E) {
    __shared__ int s[2048];
    const int t = threadIdx.x;
    int v0 = (t < NBUCK) ? bucket_cnt[t] : 0;
    int v1 = (t + 1024 < NBUCK) ? bucket_cnt[t + 1024] : 0;
    s[t] = v0; s[t + 1024] = v1;
    __syncthreads();
    for (int off = 1; off < 2048; off <<= 1) {
        int a0 = (t >= off) ? s[t - off] : 0;
        int a1 = (t + 1024 >= off) ? s[t + 1024 - off] : 0;
        __syncthreads();
        s[t] += a0; s[t + 1024] += a1;
        __syncthreads();
    }
    if (t < NBUCK) {
        int e0 = s[t] - v0;
        bucket_start[t] = e0; bucket_cursor[t] = e0;
    }
    if (t + 1024 < NBUCK) {
        int e1 = s[t + 1024] - v1;
        bucket_start[t + 1024] = e1; bucket_cursor[t + 1024] = e1;
    }
    if (t == 0) bucket_start[NBUCK] = E;
}

// Phase A: scatter packed edges into bucket-grouped csr_tmp.
// payload = (dst&63)<<17 | src. write frontier = NBUCK lines (L2-resident).
__global__ __launch_bounds__(256) void place_kernel(
        const int* __restrict__ src, const int* __restrict__ dst,
        int* __restrict__ bucket_cursor, int* __restrict__ csr_tmp, int E) {
    __shared__ int hist[NBUCK];
    const int t = threadIdx.x;
    for (int i = t; i < NBUCK; i += 256) hist[i] = 0;
    __syncthreads();
    const int base = blockIdx.x * 4096;
    int pay[16], rb[16];
#pragma unroll
    for (int j = 0; j < 16; j++) {
        int e = base + j * 256 + t;
        if (e < E) {
            int d = dst[e];
            int b = d >> 6;
            int r = atomicAdd(&hist[b], 1);       // r < 4096 (12 bits)
            pay[j] = ((d & 63) << 17) | src[e];
            rb[j] = (r << 11) | b;                // b < 2048 (11 bits)
        } else rb[j] = -1;
    }
    __syncthreads();
    for (int i = t; i < NBUCK; i += 256) {
        int h = hist[i];
        hist[i] = h ? atomicAdd(&bucket_cursor[i], h) : 0;
    }
    __syncthreads();
#pragma unroll
    for (int j = 0; j < 16; j++) {
        if (rb[j] >= 0) {
            int b = rb[j] & 2047;
            int r = rb[j] >> 11;
            csr_tmp[hist[b] + r] = pay[j];
        }
    }
}

// degree -> dinv only (replaces bsort; no node sort needed anymore)
__global__ __launch_bounds__(256) void degree_kernel(
        const int* __restrict__ bucket_start, const int* __restrict__ csr_tmp,
        float* __restrict__ dinv, int N) {
    __shared__ int c[64];
    const int b = blockIdx.x;
    const int t = threadIdx.x;
    if (t < 64) c[t] = 0;
    __syncthreads();
    const int start = bucket_start[b];
    const int end = bucket_start[b + 1];
    for (int e = start + t; e < end; e += 256)
        atomicAdd(&c[csr_tmp[e] >> 17], 1);
    __syncthreads();
    if (t < 64) {
        int node = (b << 6) + t;
        if (node < N) dinv[node] = rsqrtf((float)c[t] + 1.0f);
    }
}

// --- edge-parallel bf16 aggregation over PRESCALED zs = dinv*z -------------
// Block b owns bucket b (64 nodes). Edges consumed flat from csr_tmp; each
// F/8-lane group handles one edge: gather 16B/lane, ds_add_f32 into the LDS
// fp32 tile. Epilogue: out[i] = dinv[i]*(acc[i] + zs[i]) (+bias/relu L1MODE,
// *dinv prescale-out). LDS row stride F+8 with (ld&7) base offset spreads
// banks (ld random per edge => ~2-way, free).
template<int F, bool L1MODE, bool PRESCALE_OUT>
__global__ __launch_bounds__(256) void agg_ep_kernel(
        const unsigned short* __restrict__ z, const int* __restrict__ bucket_start,
        const int* __restrict__ csr_tmp, const float* __restrict__ dinv,
        const float* __restrict__ bias, unsigned short* __restrict__ out, int N) {
    constexpr int G  = F / 8;          // lanes per edge
    constexpr int NG = 256 / G;        // edges in flight per block
    constexpr int FP = F + 8;          // padded LDS row (swizzle room)
    __shared__ float acc[64 * FP];
    const int t = threadIdx.x;
    const int b = blockIdx.x;
    for (int i = t; i < 16 * FP; i += 256)
        *(float4*)&acc[i * 4] = float4{0.f, 0.f, 0.f, 0.f};
    __syncthreads();
    const int start = bucket_start[b];
    const int end   = bucket_start[b + 1];
    const int g  = t / G;
    const int c0 = (t % G) * 8;

    auto accum = [&](int p, const ushort8v& u) {
        int ld = p >> 17;
        float* a = &acc[ld * FP + c0 + (ld & 7)];
        float f[8];
        unpack8(u, f);
#pragma unroll
        for (int j = 0; j < 8; j++) atomicAdd(&a[j], f[j]);   // ds_add_f32
    };

    int e = start + g;
    for (; e + 3 * NG < end; e += 4 * NG) {      // U=4: 4 gathers in flight
        int p0 = csr_tmp[e];
        int p1 = csr_tmp[e + NG];
        int p2 = csr_tmp[e + 2 * NG];
        int p3 = csr_tmp[e + 3 * NG];
        ushort8v u0 = *(const ushort8v*)&z[(size_t)(p0 & 0x1FFFF) * F + c0];
        ushort8v u1 = *(const ushort8v*)&z[(size_t)(p1 & 0x1FFFF) * F + c0];
        ushort8v u2 = *(const ushort8v*)&z[(size_t)(p2 & 0x1FFFF) * F + c0];
        ushort8v u3 = *(const ushort8v*)&z[(size_t)(p3 & 0x1FFFF) * F + c0];
        accum(p0, u0); accum(p1, u1); accum(p2, u2); accum(p3, u3);
    }
    for (; e < end; e += NG) {                   // tail (<4 per lane)
        int p0 = csr_tmp[e];
        ushort8v u0 = *(const ushort8v*)&z[(size_t)(p0 & 0x1FFFF) * F + c0];
        accum(p0, u0);
    }
    __syncthreads();

    const int base = b << 6;
    for (int nl = t / G; nl < 64; nl += NG) {
        int node = base + nl;
        if (node >= N) break;                    // nodes monotone in loop
        const float di = dinv[node];
        ushort8v us = *(const ushort8v*)&z[(size_t)node * F + c0];
        float fs[8];
        unpack8(us, fs);
        const float* a = &acc[nl * FP + c0 + (nl & 7)];
        float r[8];
#pragma unroll
        for (int j = 0; j < 8; j++) r[j] = di * (a[j] + fs[j]);
        if (L1MODE) {
#pragma unroll
            for (int j = 0; j < 8; j++) r[j] = fmaxf(r[j] + bias[c0 + j], 0.f);
        }
        if (PRESCALE_OUT) {
#pragma unroll
            for (int j = 0; j < 8; j++) r[j] *= di;
        }
        *(ushort8v*)&out[(size_t)node * F + c0] = pack8(r);
    }
}

// --- register-tiled GEMM: 64-row x MB-col tile per 256-thread block ---------
// A input fp32 or bf16 (converted to fp32 in LDS staging); epilogue:
// optional bias+relu, *dinv[row] prescale, bf16 output.
template<int K, int M, int MB, int RT, bool BIAS_RELU, bool PRESCALE, bool INBF, bool OUTBF>
__global__ __launch_bounds__(256) void gemm_kernel(
        const void* __restrict__ Av, const float* __restrict__ W,
        const float* __restrict__ bias, const float* __restrict__ dinv,
        void* __restrict__ outv, int N) {
    constexpr int CG = MB / 4;
    constexpr int TM = (256 / CG) * RT;
    constexpr int KP = K + 4;            // 2-way bank alias on As reads (free)
    constexpr int MSPLIT = M / MB;
    static_assert(TM == 64, "tile rows");
    __shared__ float As[TM * KP];
    __shared__ float Ws[K * MB];
    __shared__ float bs[MB];
    const int t = threadIdx.x;
    const int base = (blockIdx.x / MSPLIT) * TM;
    const int colb = (blockIdx.x % MSPLIT) * MB;
    const int rows_valid = min(TM, N - base);
    if (INBF) {
        constexpr int KD8 = K / 8;
        const unsigned short* A = (const unsigned short*)Av;
        for (int idx = t; idx < TM * KD8; idx += 256) {
            int row = idx / KD8, kc = idx % KD8;
            if (row < rows_valid) {
                ushort8v u = *(const ushort8v*)&A[(size_t)(base + row) * K + kc * 8];
                float4 lo = {bf_to_f(u[0]), bf_to_f(u[1]), bf_to_f(u[2]), bf_to_f(u[3])};
                float4 hi = {bf_to_f(u[4]), bf_to_f(u[5]), bf_to_f(u[6]), bf_to_f(u[7])};
                *(float4*)&As[row * KP + kc * 8] = lo;
                *(float4*)&As[row * KP + kc * 8 + 4] = hi;
            }
        }
    } else {
        constexpr int KD4 = K / 4;
        const float* A = (const float*)Av;
        for (int idx = t; idx < TM * KD4; idx += 256) {
            int row = idx / KD4, kc = idx % KD4;
            if (row < rows_valid)
                *(float4*)&As[row * KP + kc * 4] = *(const float4*)&A[(size_t)(base + row) * K + kc * 4];
        }
    }
    constexpr int MD4 = MB / 4;
    for (int idx = t; idx < K * MD4; idx += 256) {
        int k = idx / MD4, c4 = idx % MD4;
        *(float4*)&Ws[k * MB + c4 * 4] = *(const float4*)&W[(size_t)k * M + colb + c4 * 4];
    }
    if (BIAS_RELU && t < MB) bs[t] = bias[colb + t];
    __syncthreads();

    const int tc = t % CG;
    const int r0 = (t / CG) * RT;
    const int c0 = tc * 4;
    float4 acc[RT];
#pragma unroll
    for (int r = 0; r < RT; r++) acc[r] = {0.f, 0.f, 0.f, 0.f};

#pragma unroll 4
    for (int k = 0; k < K; k += 4) {
        float4 w0 = *(const float4*)&Ws[(k + 0) * MB + c0];
        float4 w1 = *(const float4*)&Ws[(k + 1) * MB + c0];
        float4 w2 = *(const float4*)&Ws[(k + 2) * MB + c0];
        float4 w3 = *(const float4*)&Ws[(k + 3) * MB + c0];
#pragma unroll
        for (int r = 0; r < RT; r++) {
            float4 av = *(const float4*)&As[(r0 + r) * KP + k];
            acc[r].x += av.x * w0.x + av.y * w1.x + av.z * w2.x + av.w * w3.x;
            acc[r].y += av.x * w0.y + av.y * w1.y + av.z * w2.y + av.w * w3.y;
            acc[r].z += av.x * w0.z + av.y * w1.z + av.z * w2.z + av.w * w3.z;
            acc[r].w += av.x * w0.w + av.y * w1.w + av.z * w2.w + av.w * w3.w;
        }
    }
#pragma unroll
    for (int r = 0; r < RT; r++) {
        int row = base + r0 + r;
        if (row < N) {
            float4 v = acc[r];
            if (BIAS_RELU) {
                float4 bv = *(const float4*)&bs[c0];
                v.x = fmaxf(v.x + bv.x, 0.f); v.y = fmaxf(v.y + bv.y, 0.f);
                v.z = fmaxf(v.z + bv.z, 0.f); v.w = fmaxf(v.w + bv.w, 0.f);
            }
            if (PRESCALE) {
                float d = dinv[row];
                v.x *= d; v.y *= d; v.z *= d; v.w *= d;
            }
            if (OUTBF) {
                ushort4 u;
                u.x = f_to_bf(v.x); u.y = f_to_bf(v.y);
                u.z = f_to_bf(v.z); u.w = f_to_bf(v.w);
                *(ushort4*)&((unsigned short*)outv)[(size_t)row * M + colb + c0] = u;
            } else {
                *(float4*)&((float*)outv)[(size_t)row * M + colb + c0] = v;
            }
        }
    }
}

// --- fused FC head: h5 = relu(h4 @ Wf1 + bf1); out = tanh(h5 @ Wf2 + bf2) ---
// h4 bf16 128-wide in; h5 64x32 tile kept in LDS (aliased onto dead As).
__global__ __launch_bounds__(256) void head_kernel(
        const unsigned short* __restrict__ A, const float* __restrict__ Wf1,
        const float* __restrict__ bf1, const float* __restrict__ Wf2,
        const float* __restrict__ bf2, float* __restrict__ out, int N) {
    constexpr int K = 128, MB = 32, RT = 2, CG = 8, TM = 64, KP = K + 4;
    __shared__ float As[TM * KP];        // reused as h5 tile after k-loop
    __shared__ float Ws[K * MB];
    __shared__ float bs[MB];
    __shared__ float wt2[10 * 32];       // Wf2 transposed: wt2[m*32+k]
    __shared__ float bs2[10];
    const int t = threadIdx.x;
    const int base = blockIdx.x * TM;
    const int rows_valid = min(TM, N - base);
    constexpr int KD8 = K / 8;
    for (int idx = t; idx < TM * KD8; idx += 256) {
        int row = idx / KD8, kc = idx % KD8;
        if (row < rows_valid) {
            ushort8v u = *(const ushort8v*)&A[(size_t)(base + row) * K + kc * 8];
            float4 lo = {bf_to_f(u[0]), bf_to_f(u[1]), bf_to_f(u[2]), bf_to_f(u[3])};
            float4 hi = {bf_to_f(u[4]), bf_to_f(u[5]), bf_to_f(u[6]), bf_to_f(u[7])};
            *(float4*)&As[row * KP + kc * 8] = lo;
            *(float4*)&As[row * KP + kc * 8 + 4] = hi;
        }
    }
    for (int idx = t; idx < K * MB / 4; idx += 256) {
        int k = idx / (MB / 4), c4 = idx % (MB / 4);
        *(float4*)&Ws[k * MB + c4 * 4] = *(const float4*)&Wf1[(size_t)k * MB + c4 * 4];
    }
    if (t < MB) bs[t] = bf1[t];
    for (int idx = t; idx < 320; idx += 256)                 // strided staging
        wt2[(idx % 10) * 32 + idx / 10] = Wf2[idx];
    if (t < 10) bs2[t] = bf2[t];
    __syncthreads();

    const int tc = t % CG;
    const int r0 = (t / CG) * RT;
    const int c0 = tc * 4;
    float4 acc[RT];
#pragma unroll
    for (int r = 0; r < RT; r++) acc[r] = {0.f, 0.f, 0.f, 0.f};
#pragma unroll 4
    for (int k = 0; k < K; k += 4) {
        float4 w0 = *(const float4*)&Ws[(k + 0) * MB + c0];
        float4 w1 = *(const float4*)&Ws[(k + 1) * MB + c0];
        float4 w2 = *(const float4*)&Ws[(k + 2) * MB + c0];
        float4 w3 = *(const float4*)&Ws[(k + 3) * MB + c0];
#pragma unroll
        for (int r = 0; r < RT; r++) {
            float4 av = *(const float4*)&As[(r0 + r) * KP + k];
            acc[r].x += av.x * w0.x + av.y * w1.x + av.z * w2.x + av.w * w3.x;
            acc[r].y += av.x * w0.y + av.y * w1.y + av.z * w2.y + av.w * w3.y;
            acc[r].z += av.x * w0.z + av.y * w1.z + av.z * w2.z + av.w * w3.z;
            acc[r].w += av.x * w0.w + av.y * w1.w + av.z * w2.w + av.w * w3.w;
        }
    }
    __syncthreads();                     // all As reads done -> safe to alias
    float* h5s = As;                     // 64 x 32 tile, stride 33
#pragma unroll
    for (int r = 0; r < RT; r++) {
        int row = r0 + r;
        float4 bv = *(const float4*)&bs[c0];
        h5s[row * 33 + c0 + 0] = fmaxf(acc[r].x + bv.x, 0.f);
        h5s[row * 33 + c0 + 1] = fmaxf(acc[r].y + bv.y, 0.f);
        h5s[row * 33 + c0 + 2] = fmaxf(acc[r].z + bv.z, 0.f);
        h5s[row * 33 + c0 + 3] = fmaxf(acc[r].w + bv.w, 0.f);
    }
    __syncthreads();
    const int lrow = t >> 2;             // 0..63
    const int q = t & 3;
    const int grow = base + lrow;
    if (grow < N) {
        for (int m = q; m < 10; m += 4) {
            float a = bs2[m];
#pragma unroll
            for (int k = 0; k < 32; k++) a += h5s[lrow * 33 + k] * wt2[m * 32 + k];
            out[(size_t)grow * 10 + m] = tanhf(a);
        }
    }
}

extern "C" void kernel_launch(void* const* d_in, const int* in_sizes, int n_in,
                              void* d_out, int out_size, void* d_ws, size_t ws_size,
                              hipStream_t stream) {
    const float* x   = (const float*)d_in[0];
    const int*   ei  = (const int*)d_in[1];     // int32 on device
    const float* W1  = (const float*)d_in[2];
    const float* b1  = (const float*)d_in[3];
    const float* W2  = (const float*)d_in[4];
    const float* b2  = (const float*)d_in[5];
    const float* W3  = (const float*)d_in[6];
    const float* b3  = (const float*)d_in[7];
    const float* W4  = (const float*)d_in[8];
    const float* b4  = (const float*)d_in[9];
    const float* Wf1 = (const float*)d_in[10];
    const float* bf1 = (const float*)d_in[11];
    const float* Wf2 = (const float*)d_in[12];
    const float* bf2 = (const float*)d_in[13];

    const int N = in_sizes[0] / 128;   // 100000
    const int E = in_sizes[1] / 2;     // 1600000
    const int* e_src = ei;
    const int* e_dst = ei + E;

    char* p = (char*)d_ws;
    auto carve = [&](size_t bytes) -> void* {
        void* r = (void*)p;
        p += (bytes + 255) & ~(size_t)255;
        return r;
    };
    int*   bucket_cnt = (int*)carve(2048 * 4);
    int*   bucket_sta = (int*)carve(2080 * 4);   // NBUCK+1
    int*   bucket_cur = (int*)carve(2048 * 4);
    float* dinv       = (float*)carve((size_t)N * 4);
    int*   csr_tmp    = (int*)carve((size_t)E * 4);
    unsigned short* bufP = (unsigned short*)carve((size_t)N * 128 * 2); // bf16 ping
    unsigned short* bufQ = (unsigned short*)carve((size_t)N * 128 * 2); // bf16 pong

    const int GB = (N + 63) / 64;      // 1563 row-blocks

    // --- graph preprocessing: bucket hist, scan, place, degree->dinv ---
    zero_kernel<<<8, 256, 0, stream>>>(bucket_cnt, 2048);
    hist_kernel<<<PREB, 256, 0, stream>>>(e_dst, bucket_cnt, E);
    bucket_scan_kernel<<<1, 1024, 0, stream>>>(bucket_cnt, bucket_sta, bucket_cur, E);
    place_kernel<<<PREB, 256, 0, stream>>>(e_src, e_dst, bucket_cur, csr_tmp, E);
    degree_kernel<<<NBUCK, 256, 0, stream>>>(bucket_sta, csr_tmp, dinv, N);

    // --- L1 (128->16): prescaled GEMM -> bf16 z1; edge-parallel agg ---
    gemm_kernel<128, 16, 16, 1, false, true, false, true><<<GB, 256, 0, stream>>>(
        x, W1, nullptr, dinv, bufP, N);
    agg_ep_kernel<16, true, true><<<NBUCK, 256, 0, stream>>>(
        bufP, bucket_sta, csr_tmp, dinv, b1, bufQ, N);

    // --- L2 (16->32): agg, GEMM -> bf16 z2 ---
    agg_ep_kernel<16, false, false><<<NBUCK, 256, 0, stream>>>(
        bufQ, bucket_sta, csr_tmp, dinv, nullptr, bufP, N);
    gemm_kernel<16, 32, 32, 2, true, true, true, true><<<GB, 256, 0, stream>>>(
        bufP, W2, b2, dinv, bufQ, N);

    // --- L3 (32->64): agg, GEMM -> bf16 z3 ---
    agg_ep_kernel<32, false, false><<<NBUCK, 256, 0, stream>>>(
        bufQ, bucket_sta, csr_tmp, dinv, nullptr, bufP, N);
    gemm_kernel<32, 64, 64, 4, true, true, true, true><<<GB, 256, 0, stream>>>(
        bufP, W3, b3, dinv, bufQ, N);

    // --- L4 (64->128): agg, M-split GEMM -> bf16 h4 ---
    agg_ep_kernel<64, false, false><<<NBUCK, 256, 0, stream>>>(
        bufQ, bucket_sta, csr_tmp, dinv, nullptr, bufP, N);
    gemm_kernel<64, 128, 64, 4, true, false, true, true><<<GB * 2, 256, 0, stream>>>(
        bufP, W4, b4, nullptr, bufQ, N);

    // --- fused FC head: relu(h4 Wf1 + bf1) -> tanh(. Wf2 + bf2) ---
    head_kernel<<<GB, 256, 0, stream>>>(bufQ, Wf1, bf1, Wf2, bf2, (float*)d_out, N);
}

// Round 2
// 345.674 us; speedup vs baseline: 4.1521x; 4.1521x over previous
//
#include <hip/hip_runtime.h>
#include <hip/hip_bf16.h>
#include <cmath>

// ---------------------------------------------------------------------------
// GCN: out = tanh(relu(relu(relu(relu(P(P(P(P(xW1+..)..) .. ))Wf1+bf1)Wf2+bf2
// P = D^-1/2 (A+I) D^-1/2 via CSR (dst-sorted) gather-sum, no float atomics.
// R6-R12: bucketed CSR build + wave-per-node agg + bf16 transport + fused
// head (402.7us). R13 FAILED: edge-parallel LDS-atomic agg -> DS atomic unit
// serializes at ~1 lane-op/cycle/CU (VALUBusy 1.2%), 13x regression.
// R14: group-per-node agg. G=F/8 lanes own a node; each lane keeps 8
// channels in registers across ALL the node's edges (U=4 gathers in flight,
// no cross-lane reduce, no LDS, no atomics). Preprocessing + GEMMs = R12.
// ---------------------------------------------------------------------------

#define NBUCK 391              // ceil(100000/256)
#define PREB  391              // ceil(E/4096) edge-phase blocks (16 edges/thread)

typedef __attribute__((ext_vector_type(8))) unsigned short ushort8v;

__device__ __forceinline__ unsigned short f_to_bf(float v) {
    unsigned u = __float_as_uint(v);
    return (unsigned short)((u + 0x7FFF + ((u >> 16) & 1)) >> 16);   // RTN-even
}
__device__ __forceinline__ float bf_to_f(unsigned short v) {
    return __uint_as_float((unsigned)v << 16);
}

__device__ __forceinline__ void unpack8(const ushort8v& u, float* f) {
#pragma unroll
    for (int j = 0; j < 8; j++) f[j] = bf_to_f(u[j]);
}
__device__ __forceinline__ ushort8v pack8(const float* f) {
    ushort8v u;
#pragma unroll
    for (int j = 0; j < 8; j++) u[j] = f_to_bf(f[j]);
    return u;
}

__global__ void zero_kernel(int* p, int n) {
    int i = blockIdx.x * 256 + threadIdx.x;
    if (i < n) p[i] = 0;
}

// bucket histogram only (16 edges/thread, LDS-aggregated)
__global__ __launch_bounds__(256) void hist_kernel(
        const int* __restrict__ dst, int* __restrict__ bucket_cnt, int E) {
    __shared__ int bh[NBUCK];
    const int t = threadIdx.x;
    for (int i = t; i < NBUCK; i += 256) bh[i] = 0;
    __syncthreads();
    const int base = blockIdx.x * 4096;
#pragma unroll
    for (int j = 0; j < 16; j++) {
        int e = base + j * 256 + t;
        if (e < E) atomicAdd(&bh[dst[e] >> 8], 1);
    }
    __syncthreads();
    for (int i = t; i < NBUCK; i += 256)
        if (bh[i]) atomicAdd(&bucket_cnt[i], bh[i]);
}

// exclusive scan of bucket_cnt[NBUCK] -> bucket_start (ro) + bucket_cursor (rw)
__global__ void bucket_scan_kernel(const int* __restrict__ bucket_cnt,
                                   int* __restrict__ bucket_start,
                                   int* __restrict__ bucket_cursor, int E) {
    __shared__ int s[512];
    int t = threadIdx.x;
    int v = (t < NBUCK) ? bucket_cnt[t] : 0;
    s[t] = v; __syncthreads();
    for (int off = 1; off < 512; off <<= 1) {
        int x = (t >= off) ? s[t - off] : 0;
        __syncthreads();
        s[t] += x;
        __syncthreads();
    }
    if (t < NBUCK) {
        int excl = s[t] - v;
        bucket_start[t] = excl;
        bucket_cursor[t] = excl;
    }
    if (t == 0) bucket_start[NBUCK] = E;
}

// Phase A: scatter packed edges into bucket-grouped csr_tmp.
// payload = (dst&255)<<17 | src. write frontier = 391 lines (L2-resident).
__global__ __launch_bounds__(256) void place_kernel(
        const int* __restrict__ src, const int* __restrict__ dst,
        int* __restrict__ bucket_cursor, int* __restrict__ csr_tmp, int E) {
    __shared__ int hist[NBUCK];
    const int t = threadIdx.x;
    for (int i = t; i < NBUCK; i += 256) hist[i] = 0;
    __syncthreads();
    const int base = blockIdx.x * 4096;
    int pay[16], rb[16];
#pragma unroll
    for (int j = 0; j < 16; j++) {
        int e = base + j * 256 + t;
        if (e < E) {
            int d = dst[e];
            int b = d >> 8;
            int r = atomicAdd(&hist[b], 1);       // r < 4096
            pay[j] = ((d & 255) << 17) | src[e];
            rb[j] = (r << 9) | b;                 // b < 512
        } else rb[j] = -1;
    }
    __syncthreads();
    for (int i = t; i < NBUCK; i += 256) {
        int h = hist[i];
        hist[i] = h ? atomicAdd(&bucket_cursor[i], h) : 0;
    }
    __syncthreads();
#pragma unroll
    for (int j = 0; j < 16; j++) {
        if (rb[j] >= 0) {
            int b = rb[j] & 511;
            int r = rb[j] >> 9;
            csr_tmp[hist[b] + r] = pay[j];
        }
    }
}

// Phase B: one block per bucket -> per-node CSR (row_ptr + csr_src) + dinv.
__global__ __launch_bounds__(256) void bsort_kernel(
        const int* __restrict__ bucket_start, const int* __restrict__ csr_tmp,
        int* __restrict__ row_ptr, int* __restrict__ csr_src,
        float* __restrict__ dinv, int N, int E) {
    __shared__ int c[256], s[256], cur[256];
    const int b = blockIdx.x;
    const int t = threadIdx.x;
    const int start = bucket_start[b];
    const int end = bucket_start[b + 1];
    c[t] = 0;
    __syncthreads();
    for (int e = start + t; e < end; e += 256)
        atomicAdd(&c[csr_tmp[e] >> 17], 1);
    __syncthreads();
    int v = c[t];
    s[t] = v; __syncthreads();
    for (int off = 1; off < 256; off <<= 1) {
        int x = (t >= off) ? s[t - off] : 0;
        __syncthreads();
        s[t] += x;
        __syncthreads();
    }
    int excl = s[t] - v;
    int node = (b << 8) + t;
    if (node < N) {
        row_ptr[node] = start + excl;
        dinv[node] = rsqrtf((float)v + 1.0f);
    }
    cur[t] = start + excl;
    if (b == NBUCK - 1 && t == 0) row_ptr[N] = E;
    __syncthreads();
    for (int e = start + t; e < end; e += 256) {
        int p = csr_tmp[e];
        int pos = atomicAdd(&cur[p >> 17], 1);
        csr_src[pos] = p & 0x1FFFF;
    }
}

// --- group-per-node bf16 aggregation over PRESCALED input zs = dinv*z ------
// G = F/8 lanes own one node; lane keeps 8 channels in registers across all
// the node's edges. U=4 independent gathers in flight per lane. No LDS, no
// atomics, no cross-lane reduce. out[i] = dinv[i]*(sum_e zs[src_e] + zs[i]);
// optional bias+relu (L1MODE), optional output prescale.
template<int F, bool L1MODE, bool PRESCALE_OUT>
__global__ __launch_bounds__(256) void agg_gpn_kernel(
        const unsigned short* __restrict__ z, const int* __restrict__ row_ptr,
        const int* __restrict__ csr_src, const float* __restrict__ dinv,
        const float* __restrict__ bias, unsigned short* __restrict__ out, int N) {
    constexpr int G  = F / 8;          // lanes per node
    constexpr int NPB = 256 / G;       // nodes per block
    const int t = threadIdx.x;
    const int c0 = (t % G) * 8;
    const int node = blockIdx.x * NPB + t / G;
    if (node >= N) return;             // group-uniform exit, no barriers below
    const int start = row_ptr[node];
    const int end   = row_ptr[node + 1];
    float acc[8];
#pragma unroll
    for (int j = 0; j < 8; j++) acc[j] = 0.f;
    int e = start;
    while (e + 3 < end) {              // U=4: 4 independent gathers in flight
        int s0 = csr_src[e];
        int s1 = csr_src[e + 1];
        int s2 = csr_src[e + 2];
        int s3 = csr_src[e + 3];
        ushort8v u0 = *(const ushort8v*)&z[(size_t)s0 * F + c0];
        ushort8v u1 = *(const ushort8v*)&z[(size_t)s1 * F + c0];
        ushort8v u2 = *(const ushort8v*)&z[(size_t)s2 * F + c0];
        ushort8v u3 = *(const ushort8v*)&z[(size_t)s3 * F + c0];
        float f0[8], f1[8], f2[8], f3[8];
        unpack8(u0, f0); unpack8(u1, f1);
        unpack8(u2, f2); unpack8(u3, f3);
#pragma unroll
        for (int j = 0; j < 8; j++) acc[j] += (f0[j] + f1[j]) + (f2[j] + f3[j]);
        e += 4;
    }
    if (e + 1 < end) {                 // U=2
        int s0 = csr_src[e];
        int s1 = csr_src[e + 1];
        ushort8v u0 = *(const ushort8v*)&z[(size_t)s0 * F + c0];
        ushort8v u1 = *(const ushort8v*)&z[(size_t)s1 * F + c0];
        float f0[8], f1[8];
        unpack8(u0, f0); unpack8(u1, f1);
#pragma unroll
        for (int j = 0; j < 8; j++) acc[j] += f0[j] + f1[j];
        e += 2;
    }
    if (e < end) {                     // tail
        int s0 = csr_src[e];
        ushort8v u0 = *(const ushort8v*)&z[(size_t)s0 * F + c0];
        float f0[8];
        unpack8(u0, f0);
#pragma unroll
        for (int j = 0; j < 8; j++) acc[j] += f0[j];
    }
    const float di = dinv[node];
    ushort8v us = *(const ushort8v*)&z[(size_t)node * F + c0];
    float fs[8], r[8];
    unpack8(us, fs);
#pragma unroll
    for (int j = 0; j < 8; j++) r[j] = di * (acc[j] + fs[j]);
    if (L1MODE) {
#pragma unroll
        for (int j = 0; j < 8; j++) r[j] = fmaxf(r[j] + bias[c0 + j], 0.f);
    }
    if (PRESCALE_OUT) {
#pragma unroll
        for (int j = 0; j < 8; j++) r[j] *= di;
    }
    *(ushort8v*)&out[(size_t)node * F + c0] = pack8(r);
}

// --- register-tiled GEMM: 64-row x MB-col tile per 256-thread block ---------
// A input fp32 or bf16 (converted to fp32 in LDS staging); epilogue:
// optional bias+relu, *dinv[row] prescale, bf16 output.
template<int K, int M, int MB, int RT, bool BIAS_RELU, bool PRESCALE, bool INBF, bool OUTBF>
__global__ __launch_bounds__(256) void gemm_kernel(
        const void* __restrict__ Av, const float* __restrict__ W,
        const float* __restrict__ bias, const float* __restrict__ dinv,
        void* __restrict__ outv, int N) {
    constexpr int CG = MB / 4;
    constexpr int TM = (256 / CG) * RT;
    constexpr int KP = K + 4;            // 2-way bank alias on As reads (free)
    constexpr int MSPLIT = M / MB;
    static_assert(TM == 64, "tile rows");
    __shared__ float As[TM * KP];
    __shared__ float Ws[K * MB];
    __shared__ float bs[MB];
    const int t = threadIdx.x;
    const int base = (blockIdx.x / MSPLIT) * TM;
    const int colb = (blockIdx.x % MSPLIT) * MB;
    const int rows_valid = min(TM, N - base);
    if (INBF) {
        constexpr int KD8 = K / 8;
        const unsigned short* A = (const unsigned short*)Av;
        for (int idx = t; idx < TM * KD8; idx += 256) {
            int row = idx / KD8, kc = idx % KD8;
            if (row < rows_valid) {
                ushort8v u = *(const ushort8v*)&A[(size_t)(base + row) * K + kc * 8];
                float4 lo = {bf_to_f(u[0]), bf_to_f(u[1]), bf_to_f(u[2]), bf_to_f(u[3])};
                float4 hi = {bf_to_f(u[4]), bf_to_f(u[5]), bf_to_f(u[6]), bf_to_f(u[7])};
                *(float4*)&As[row * KP + kc * 8] = lo;
                *(float4*)&As[row * KP + kc * 8 + 4] = hi;
            }
        }
    } else {
        constexpr int KD4 = K / 4;
        const float* A = (const float*)Av;
        for (int idx = t; idx < TM * KD4; idx += 256) {
            int row = idx / KD4, kc = idx % KD4;
            if (row < rows_valid)
                *(float4*)&As[row * KP + kc * 4] = *(const float4*)&A[(size_t)(base + row) * K + kc * 4];
        }
    }
    constexpr int MD4 = MB / 4;
    for (int idx = t; idx < K * MD4; idx += 256) {
        int k = idx / MD4, c4 = idx % MD4;
        *(float4*)&Ws[k * MB + c4 * 4] = *(const float4*)&W[(size_t)k * M + colb + c4 * 4];
    }
    if (BIAS_RELU && t < MB) bs[t] = bias[colb + t];
    __syncthreads();

    const int tc = t % CG;
    const int r0 = (t / CG) * RT;
    const int c0 = tc * 4;
    float4 acc[RT];
#pragma unroll
    for (int r = 0; r < RT; r++) acc[r] = {0.f, 0.f, 0.f, 0.f};

#pragma unroll 4
    for (int k = 0; k < K; k += 4) {
        float4 w0 = *(const float4*)&Ws[(k + 0) * MB + c0];
        float4 w1 = *(const float4*)&Ws[(k + 1) * MB + c0];
        float4 w2 = *(const float4*)&Ws[(k + 2) * MB + c0];
        float4 w3 = *(const float4*)&Ws[(k + 3) * MB + c0];
#pragma unroll
        for (int r = 0; r < RT; r++) {
            float4 av = *(const float4*)&As[(r0 + r) * KP + k];
            acc[r].x += av.x * w0.x + av.y * w1.x + av.z * w2.x + av.w * w3.x;
            acc[r].y += av.x * w0.y + av.y * w1.y + av.z * w2.y + av.w * w3.y;
            acc[r].z += av.x * w0.z + av.y * w1.z + av.z * w2.z + av.w * w3.z;
            acc[r].w += av.x * w0.w + av.y * w1.w + av.z * w2.w + av.w * w3.w;
        }
    }
#pragma unroll
    for (int r = 0; r < RT; r++) {
        int row = base + r0 + r;
        if (row < N) {
            float4 v = acc[r];
            if (BIAS_RELU) {
                float4 bv = *(const float4*)&bs[c0];
                v.x = fmaxf(v.x + bv.x, 0.f); v.y = fmaxf(v.y + bv.y, 0.f);
                v.z = fmaxf(v.z + bv.z, 0.f); v.w = fmaxf(v.w + bv.w, 0.f);
            }
            if (PRESCALE) {
                float d = dinv[row];
                v.x *= d; v.y *= d; v.z *= d; v.w *= d;
            }
            if (OUTBF) {
                ushort4 u;
                u.x = f_to_bf(v.x); u.y = f_to_bf(v.y);
                u.z = f_to_bf(v.z); u.w = f_to_bf(v.w);
                *(ushort4*)&((unsigned short*)outv)[(size_t)row * M + colb + c0] = u;
            } else {
                *(float4*)&((float*)outv)[(size_t)row * M + colb + c0] = v;
            }
        }
    }
}

// --- fused FC head: h5 = relu(h4 @ Wf1 + bf1); out = tanh(h5 @ Wf2 + bf2) ---
// h4 bf16 128-wide in; h5 64x32 tile kept in LDS (aliased onto dead As).
__global__ __launch_bounds__(256) void head_kernel(
        const unsigned short* __restrict__ A, const float* __restrict__ Wf1,
        const float* __restrict__ bf1, const float* __restrict__ Wf2,
        const float* __restrict__ bf2, float* __restrict__ out, int N) {
    constexpr int K = 128, MB = 32, RT = 2, CG = 8, TM = 64, KP = K + 4;
    __shared__ float As[TM * KP];        // reused as h5 tile after k-loop
    __shared__ float Ws[K * MB];
    __shared__ float bs[MB];
    __shared__ float wt2[10 * 32];       // Wf2 transposed: wt2[m*32+k]
    __shared__ float bs2[10];
    const int t = threadIdx.x;
    const int base = blockIdx.x * TM;
    const int rows_valid = min(TM, N - base);
    constexpr int KD8 = K / 8;
    for (int idx = t; idx < TM * KD8; idx += 256) {
        int row = idx / KD8, kc = idx % KD8;
        if (row < rows_valid) {
            ushort8v u = *(const ushort8v*)&A[(size_t)(base + row) * K + kc * 8];
            float4 lo = {bf_to_f(u[0]), bf_to_f(u[1]), bf_to_f(u[2]), bf_to_f(u[3])};
            float4 hi = {bf_to_f(u[4]), bf_to_f(u[5]), bf_to_f(u[6]), bf_to_f(u[7])};
            *(float4*)&As[row * KP + kc * 8] = lo;
            *(float4*)&As[row * KP + kc * 8 + 4] = hi;
        }
    }
    for (int idx = t; idx < K * MB / 4; idx += 256) {
        int k = idx / (MB / 4), c4 = idx % (MB / 4);
        *(float4*)&Ws[k * MB + c4 * 4] = *(const float4*)&Wf1[(size_t)k * MB + c4 * 4];
    }
    if (t < MB) bs[t] = bf1[t];
    for (int idx = t; idx < 320; idx += 256)                 // strided staging
        wt2[(idx % 10) * 32 + idx / 10] = Wf2[idx];
    if (t < 10) bs2[t] = bf2[t];
    __syncthreads();

    const int tc = t % CG;
    const int r0 = (t / CG) * RT;
    const int c0 = tc * 4;
    float4 acc[RT];
#pragma unroll
    for (int r = 0; r < RT; r++) acc[r] = {0.f, 0.f, 0.f, 0.f};
#pragma unroll 4
    for (int k = 0; k < K; k += 4) {
        float4 w0 = *(const float4*)&Ws[(k + 0) * MB + c0];
        float4 w1 = *(const float4*)&Ws[(k + 1) * MB + c0];
        float4 w2 = *(const float4*)&Ws[(k + 2) * MB + c0];
        float4 w3 = *(const float4*)&Ws[(k + 3) * MB + c0];
#pragma unroll
        for (int r = 0; r < RT; r++) {
            float4 av = *(const float4*)&As[(r0 + r) * KP + k];
            acc[r].x += av.x * w0.x + av.y * w1.x + av.z * w2.x + av.w * w3.x;
            acc[r].y += av.x * w0.y + av.y * w1.y + av.z * w2.y + av.w * w3.y;
            acc[r].z += av.x * w0.z + av.y * w1.z + av.z * w2.z + av.w * w3.z;
            acc[r].w += av.x * w0.w + av.y * w1.w + av.z * w2.w + av.w * w3.w;
        }
    }
    __syncthreads();                     // all As reads done -> safe to alias
    float* h5s = As;                     // 64 x 32 tile, stride 33
#pragma unroll
    for (int r = 0; r < RT; r++) {
        int row = r0 + r;
        float4 bv = *(const float4*)&bs[c0];
        h5s[row * 33 + c0 + 0] = fmaxf(acc[r].x + bv.x, 0.f);
        h5s[row * 33 + c0 + 1] = fmaxf(acc[r].y + bv.y, 0.f);
        h5s[row * 33 + c0 + 2] = fmaxf(acc[r].z + bv.z, 0.f);
        h5s[row * 33 + c0 + 3] = fmaxf(acc[r].w + bv.w, 0.f);
    }
    __syncthreads();
    const int lrow = t >> 2;             // 0..63
    const int q = t & 3;
    const int grow = base + lrow;
    if (grow < N) {
        for (int m = q; m < 10; m += 4) {
            float a = bs2[m];
#pragma unroll
            for (int k = 0; k < 32; k++) a += h5s[lrow * 33 + k] * wt2[m * 32 + k];
            out[(size_t)grow * 10 + m] = tanhf(a);
        }
    }
}

extern "C" void kernel_launch(void* const* d_in, const int* in_sizes, int n_in,
                              void* d_out, int out_size, void* d_ws, size_t ws_size,
                              hipStream_t stream) {
    const float* x   = (const float*)d_in[0];
    const int*   ei  = (const int*)d_in[1];     // int32 on device
    const float* W1  = (const float*)d_in[2];
    const float* b1  = (const float*)d_in[3];
    const float* W2  = (const float*)d_in[4];
    const float* b2  = (const float*)d_in[5];
    const float* W3  = (const float*)d_in[6];
    const float* b3  = (const float*)d_in[7];
    const float* W4  = (const float*)d_in[8];
    const float* b4  = (const float*)d_in[9];
    const float* Wf1 = (const float*)d_in[10];
    const float* bf1 = (const float*)d_in[11];
    const float* Wf2 = (const float*)d_in[12];
    const float* bf2 = (const float*)d_in[13];

    const int N = in_sizes[0] / 128;   // 100000
    const int E = in_sizes[1] / 2;     // 1600000
    const int* e_src = ei;
    const int* e_dst = ei + E;

    char* p = (char*)d_ws;
    auto carve = [&](size_t bytes) -> void* {
        void* r = (void*)p;
        p += (bytes + 255) & ~(size_t)255;
        return r;
    };
    int*   bucket_cnt = (int*)carve(512 * 4);
    int*   bucket_sta = (int*)carve(512 * 4);
    int*   bucket_cur = (int*)carve(512 * 4);
    float* dinv       = (float*)carve((size_t)N * 4);
    int*   row_ptr    = (int*)carve((size_t)(N + 1) * 4);
    int*   csr_tmp    = (int*)carve((size_t)E * 4);
    int*   csr_src    = (int*)carve((size_t)E * 4);
    unsigned short* bufP = (unsigned short*)carve((size_t)N * 128 * 2); // bf16 ping
    unsigned short* bufQ = (unsigned short*)carve((size_t)N * 128 * 2); // bf16 pong

    const int GB  = (N + 63) / 64;     // 1563 row-blocks
    const int AG16 = (N + 127) / 128;  // F=16: 128 nodes/block
    const int AG32 = (N + 63) / 64;    // F=32: 64 nodes/block
    const int AG64 = (N + 31) / 32;    // F=64: 32 nodes/block

    // --- graph preprocessing: bucket hist, scan, place, bsort(+dinv) ---
    zero_kernel<<<2, 256, 0, stream>>>(bucket_cnt, 512);
    hist_kernel<<<PREB, 256, 0, stream>>>(e_dst, bucket_cnt, E);
    bucket_scan_kernel<<<1, 512, 0, stream>>>(bucket_cnt, bucket_sta, bucket_cur, E);
    place_kernel<<<PREB, 256, 0, stream>>>(e_src, e_dst, bucket_cur, csr_tmp, E);
    bsort_kernel<<<NBUCK, 256, 0, stream>>>(bucket_sta, csr_tmp, row_ptr, csr_src, dinv, N, E);

    // --- L1 (128->16): prescaled GEMM -> bf16 z1; group-per-node agg ---
    gemm_kernel<128, 16, 16, 1, false, true, false, true><<<GB, 256, 0, stream>>>(
        x, W1, nullptr, dinv, bufP, N);
    agg_gpn_kernel<16, true, true><<<AG16, 256, 0, stream>>>(
        bufP, row_ptr, csr_src, dinv, b1, bufQ, N);

    // --- L2 (16->32): agg, GEMM -> bf16 z2 ---
    agg_gpn_kernel<16, false, false><<<AG16, 256, 0, stream>>>(
        bufQ, row_ptr, csr_src, dinv, nullptr, bufP, N);
    gemm_kernel<16, 32, 32, 2, true, true, true, true><<<GB, 256, 0, stream>>>(
        bufP, W2, b2, dinv, bufQ, N);

    // --- L3 (32->64): agg, GEMM -> bf16 z3 ---
    agg_gpn_kernel<32, false, false><<<AG32, 256, 0, stream>>>(
        bufQ, row_ptr, csr_src, dinv, nullptr, bufP, N);
    gemm_kernel<32, 64, 64, 4, true, true, true, true><<<GB, 256, 0, stream>>>(
        bufP, W3, b3, dinv, bufQ, N);

    // --- L4 (64->128): agg, M-split GEMM -> bf16 h4 ---
    agg_gpn_kernel<64, false, false><<<AG64, 256, 0, stream>>>(
        bufQ, row_ptr, csr_src, dinv, nullptr, bufP, N);
    gemm_kernel<64, 128, 64, 4, true, false, true, true><<<GB * 2, 256, 0, stream>>>(
        bufP, W4, b4, nullptr, bufQ, N);

    // --- fused FC head: relu(h4 Wf1 + bf1) -> tanh(. Wf2 + bf2) ---
    head_kernel<<<GB, 256, 0, stream>>>(bufQ, Wf1, bf1, Wf2, bf2, (float*)d_out, N);
}

// Round 3
// 342.427 us; speedup vs baseline: 4.1914x; 1.0095x over previous
//
#include <hip/hip_runtime.h>
#include <hip/hip_bf16.h>
#include <cmath>

// ---------------------------------------------------------------------------
// GCN: out = tanh(relu(relu(relu(relu(P(P(P(P(xW1+..)..) .. ))Wf1+bf1)Wf2+bf2
// P = D^-1/2 (A+I) D^-1/2 via bucketed CSR gather-sum, no float atomics.
// R14: group-per-node register agg (345.7us). All kernels now <41us; 14
// dispatches x ~10us drain/launch + bf16 transport dominate.
// R15: dispatch-count reduction 14 -> 9:
//  - fixed-capacity buckets (BCAP=5120 = mean 4096 + 16 sigma): place uses
//    global per-bucket cursors init'ed to b*BCAP -> hist + scan DELETED.
//  - bsort also emits deg[] (explicit row lengths, padded layout).
//  - L2/L3/L4 aggs FUSED into GEMM A-staging (gather -> fp32 As directly):
//    3 launches + 22.4MB bf16 write + 22.4MB re-read + pack/unpack deleted.
//    L4 computes all 128 cols per block (CS=2 register col-split) so the
//    gather isn't duplicated by an M-split.
// ---------------------------------------------------------------------------

#define NBUCK 391              // ceil(100000/256) 256-node buckets
#define PREB  391              // ceil(E/4096) edge-phase blocks
#define BCAP  5120             // edges per bucket capacity (mean 4096, 16s)

typedef __attribute__((ext_vector_type(8))) unsigned short ushort8v;

__device__ __forceinline__ unsigned short f_to_bf(float v) {
    unsigned u = __float_as_uint(v);
    return (unsigned short)((u + 0x7FFF + ((u >> 16) & 1)) >> 16);   // RTN-even
}
__device__ __forceinline__ float bf_to_f(unsigned short v) {
    return __uint_as_float((unsigned)v << 16);
}

template<int VE> struct BFV;
template<> struct BFV<4> {
    using T = ushort4;
    __device__ static inline void unpack(const T& u, float* f) {
        f[0] = bf_to_f(u.x); f[1] = bf_to_f(u.y);
        f[2] = bf_to_f(u.z); f[3] = bf_to_f(u.w);
    }
};
template<> struct BFV<8> {
    using T = ushort8v;
    __device__ static inline void unpack(const T& u, float* f) {
#pragma unroll
        for (int j = 0; j < 8; j++) f[j] = bf_to_f(u[j]);
    }
};

__device__ __forceinline__ ushort8v pack8(const float* f) {
    ushort8v u;
#pragma unroll
    for (int j = 0; j < 8; j++) u[j] = f_to_bf(f[j]);
    return u;
}

__global__ void init_cursor_kernel(int* __restrict__ cur) {
    int i = blockIdx.x * 256 + threadIdx.x;
    if (i < NBUCK) cur[i] = i * BCAP;
}

// Phase A: scatter packed edges into fixed-capacity bucket regions.
// payload = (dst&255)<<17 | src. cursors pre-init'ed to b*BCAP.
__global__ __launch_bounds__(256) void place_kernel(
        const int* __restrict__ src, const int* __restrict__ dst,
        int* __restrict__ bucket_cursor, int* __restrict__ csr_tmp, int E) {
    __shared__ int hist[NBUCK];
    const int t = threadIdx.x;
    for (int i = t; i < NBUCK; i += 256) hist[i] = 0;
    __syncthreads();
    const int base = blockIdx.x * 4096;
    int pay[16], rb[16];
#pragma unroll
    for (int j = 0; j < 16; j++) {
        int e = base + j * 256 + t;
        if (e < E) {
            int d = dst[e];
            int b = d >> 8;
            int r = atomicAdd(&hist[b], 1);       // r < 4096 (12 bits)
            pay[j] = ((d & 255) << 17) | src[e];
            rb[j] = (r << 9) | b;                 // b < 512 (9 bits)
        } else rb[j] = -1;
    }
    __syncthreads();
    for (int i = t; i < NBUCK; i += 256) {
        int h = hist[i];
        hist[i] = h ? atomicAdd(&bucket_cursor[i], h) : 0;
    }
    __syncthreads();
#pragma unroll
    for (int j = 0; j < 16; j++) {
        if (rb[j] >= 0) {
            int b = rb[j] & 511;
            int r = rb[j] >> 9;
            csr_tmp[hist[b] + r] = pay[j];
        }
    }
}

// Phase B: one block per bucket -> per-node CSR (row_ptr + deg + csr_src,
// padded-bucket layout) + dinv.
__global__ __launch_bounds__(256) void bsort_kernel(
        const int* __restrict__ bucket_cursor, const int* __restrict__ csr_tmp,
        int* __restrict__ row_ptr, int* __restrict__ csr_src,
        int* __restrict__ degp, float* __restrict__ dinv, int N) {
    __shared__ int c[256], s[256], cur[256];
    const int b = blockIdx.x;
    const int t = threadIdx.x;
    const int start = b * BCAP;
    const int end = bucket_cursor[b];            // absolute fill end
    c[t] = 0;
    __syncthreads();
    for (int e = start + t; e < end; e += 256)
        atomicAdd(&c[csr_tmp[e] >> 17], 1);
    __syncthreads();
    int v = c[t];
    s[t] = v; __syncthreads();
    for (int off = 1; off < 256; off <<= 1) {
        int x = (t >= off) ? s[t - off] : 0;
        __syncthreads();
        s[t] += x;
        __syncthreads();
    }
    int excl = s[t] - v;
    int node = (b << 8) + t;
    if (node < N) {
        row_ptr[node] = start + excl;
        degp[node] = v;
        dinv[node] = rsqrtf((float)v + 1.0f);
    }
    cur[t] = start + excl;
    __syncthreads();
    for (int e = start + t; e < end; e += 256) {
        int p = csr_tmp[e];
        int pos = atomicAdd(&cur[p >> 17], 1);
        csr_src[pos] = p & 0x1FFFF;
    }
}

// --- group-per-node bf16 aggregation over PRESCALED input zs = dinv*z ------
// Used standalone only for L1 (bias+relu, prescale-out). G = F/8 lanes own
// one node; 8 channels/lane in registers, U=4 gathers in flight.
template<int F, bool L1MODE, bool PRESCALE_OUT>
__global__ __launch_bounds__(256) void agg_gpn_kernel(
        const unsigned short* __restrict__ z, const int* __restrict__ row_ptr,
        const int* __restrict__ degp, const int* __restrict__ csr_src,
        const float* __restrict__ dinv, const float* __restrict__ bias,
        unsigned short* __restrict__ out, int N) {
    constexpr int G  = F / 8;          // lanes per node
    constexpr int NPB = 256 / G;       // nodes per block
    const int t = threadIdx.x;
    const int c0 = (t % G) * 8;
    const int node = blockIdx.x * NPB + t / G;
    if (node >= N) return;             // group-uniform exit, no barriers below
    const int start = row_ptr[node];
    const int end   = start + degp[node];
    float acc[8];
#pragma unroll
    for (int j = 0; j < 8; j++) acc[j] = 0.f;
    int e = start;
    while (e + 3 < end) {              // U=4: 4 independent gathers in flight
        int s0 = csr_src[e];
        int s1 = csr_src[e + 1];
        int s2 = csr_src[e + 2];
        int s3 = csr_src[e + 3];
        ushort8v u0 = *(const ushort8v*)&z[(size_t)s0 * F + c0];
        ushort8v u1 = *(const ushort8v*)&z[(size_t)s1 * F + c0];
        ushort8v u2 = *(const ushort8v*)&z[(size_t)s2 * F + c0];
        ushort8v u3 = *(const ushort8v*)&z[(size_t)s3 * F + c0];
        float f0[8], f1[8], f2[8], f3[8];
        BFV<8>::unpack(u0, f0); BFV<8>::unpack(u1, f1);
        BFV<8>::unpack(u2, f2); BFV<8>::unpack(u3, f3);
#pragma unroll
        for (int j = 0; j < 8; j++) acc[j] += (f0[j] + f1[j]) + (f2[j] + f3[j]);
        e += 4;
    }
    if (e + 1 < end) {                 // U=2
        int s0 = csr_src[e];
        int s1 = csr_src[e + 1];
        ushort8v u0 = *(const ushort8v*)&z[(size_t)s0 * F + c0];
        ushort8v u1 = *(const ushort8v*)&z[(size_t)s1 * F + c0];
        float f0[8], f1[8];
        BFV<8>::unpack(u0, f0); BFV<8>::unpack(u1, f1);
#pragma unroll
        for (int j = 0; j < 8; j++) acc[j] += f0[j] + f1[j];
        e += 2;
    }
    if (e < end) {                     // tail
        int s0 = csr_src[e];
        ushort8v u0 = *(const ushort8v*)&z[(size_t)s0 * F + c0];
        float f0[8];
        BFV<8>::unpack(u0, f0);
#pragma unroll
        for (int j = 0; j < 8; j++) acc[j] += f0[j];
    }
    const float di = dinv[node];
    ushort8v us = *(const ushort8v*)&z[(size_t)node * F + c0];
    float fs[8], r[8];
    BFV<8>::unpack(us, fs);
#pragma unroll
    for (int j = 0; j < 8; j++) r[j] = di * (acc[j] + fs[j]);
    if (L1MODE) {
#pragma unroll
        for (int j = 0; j < 8; j++) r[j] = fmaxf(r[j] + bias[c0 + j], 0.f);
    }
    if (PRESCALE_OUT) {
#pragma unroll
        for (int j = 0; j < 8; j++) r[j] *= di;
    }
    *(ushort8v*)&out[(size_t)node * F + c0] = pack8(r);
}

// --- fused agg+GEMM: As[r][k] = dinv*(sum_e z[src][k] + z[r][k]); then
// out = relu(As @ W + b) [* dinv if PRESCALE], bf16 out, width MB*CS.
// CPL channels per lane during gather; CS col-splits computed in-register
// (one gather, full output width -> no M-split duplicate gathers).
template<int K, int MB, int RT, int CS, int CPL, bool PRESCALE>
__global__ __launch_bounds__(256) void gemm_agg_kernel(
        const unsigned short* __restrict__ z, const int* __restrict__ row_ptr,
        const int* __restrict__ degp, const int* __restrict__ csr_src,
        const float* __restrict__ dinv, const float* __restrict__ W,
        const float* __restrict__ bias, unsigned short* __restrict__ out, int N) {
    constexpr int CG = MB / 4;
    constexpr int TM = (256 / CG) * RT;
    constexpr int KP = K + 4;            // 2-way bank alias on As reads (free)
    constexpr int MBT = MB * CS;
    static_assert(TM == 64, "tile rows");
    __shared__ float As[TM * KP];
    __shared__ float Ws[K * MBT];
    __shared__ float bs[MBT];
    const int t = threadIdx.x;
    const int base = blockIdx.x * TM;

    {   // ---- gather-staged A (the fused aggregation) ----
        using VT = typename BFV<CPL>::T;
        constexpr int G = K / CPL;       // lanes per node
        constexpr int NPB = 256 / G;     // nodes in flight
        const int gg = t / G;
        const int ac0 = (t % G) * CPL;
        for (int r = gg; r < TM; r += NPB) {
            const int node = base + r;
            float res[CPL];
            if (node < N) {
                const int start = row_ptr[node];
                const int end = start + degp[node];
                float acc[CPL];
#pragma unroll
                for (int j = 0; j < CPL; j++) acc[j] = 0.f;
                int e = start;
                while (e + 3 < end) {    // U=4 gathers in flight
                    int s0 = csr_src[e];
                    int s1 = csr_src[e + 1];
                    int s2 = csr_src[e + 2];
                    int s3 = csr_src[e + 3];
                    VT u0 = *(const VT*)&z[(size_t)s0 * K + ac0];
                    VT u1 = *(const VT*)&z[(size_t)s1 * K + ac0];
                    VT u2 = *(const VT*)&z[(size_t)s2 * K + ac0];
                    VT u3 = *(const VT*)&z[(size_t)s3 * K + ac0];
                    float f0[CPL], f1[CPL], f2[CPL], f3[CPL];
                    BFV<CPL>::unpack(u0, f0); BFV<CPL>::unpack(u1, f1);
                    BFV<CPL>::unpack(u2, f2); BFV<CPL>::unpack(u3, f3);
#pragma unroll
                    for (int j = 0; j < CPL; j++)
                        acc[j] += (f0[j] + f1[j]) + (f2[j] + f3[j]);
                    e += 4;
                }
                if (e + 1 < end) {       // U=2
                    int s0 = csr_src[e];
                    int s1 = csr_src[e + 1];
                    VT u0 = *(const VT*)&z[(size_t)s0 * K + ac0];
                    VT u1 = *(const VT*)&z[(size_t)s1 * K + ac0];
                    float f0[CPL], f1[CPL];
                    BFV<CPL>::unpack(u0, f0); BFV<CPL>::unpack(u1, f1);
#pragma unroll
                    for (int j = 0; j < CPL; j++) acc[j] += f0[j] + f1[j];
                    e += 2;
                }
                if (e < end) {           // tail
                    int s0 = csr_src[e];
                    VT u0 = *(const VT*)&z[(size_t)s0 * K + ac0];
                    float f0[CPL];
                    BFV<CPL>::unpack(u0, f0);
#pragma unroll
                    for (int j = 0; j < CPL; j++) acc[j] += f0[j];
                }
                const float di = dinv[node];
                VT us = *(const VT*)&z[(size_t)node * K + ac0];
                float fs[CPL];
                BFV<CPL>::unpack(us, fs);
#pragma unroll
                for (int j = 0; j < CPL; j++) res[j] = di * (acc[j] + fs[j]);
            } else {
#pragma unroll
                for (int j = 0; j < CPL; j++) res[j] = 0.f;
            }
#pragma unroll
            for (int j = 0; j < CPL; j++) As[r * KP + ac0 + j] = res[j];
        }
    }
    // ---- W + bias staging ----
    constexpr int MD4 = MBT / 4;
    for (int idx = t; idx < K * MD4; idx += 256) {
        int k = idx / MD4, c4 = idx % MD4;
        *(float4*)&Ws[k * MBT + c4 * 4] = *(const float4*)&W[(size_t)k * MBT + c4 * 4];
    }
    if (t < MBT) bs[t] = bias[t];
    __syncthreads();

    const int tc = t % CG;
    const int r0 = (t / CG) * RT;
    const int c0 = tc * 4;
    float4 acc[CS][RT];
#pragma unroll
    for (int s = 0; s < CS; s++)
#pragma unroll
        for (int r = 0; r < RT; r++) acc[s][r] = {0.f, 0.f, 0.f, 0.f};

#pragma unroll 4
    for (int k = 0; k < K; k += 4) {
        float4 w[CS][4];
#pragma unroll
        for (int s = 0; s < CS; s++) {
            w[s][0] = *(const float4*)&Ws[(k + 0) * MBT + s * MB + c0];
            w[s][1] = *(const float4*)&Ws[(k + 1) * MBT + s * MB + c0];
            w[s][2] = *(const float4*)&Ws[(k + 2) * MBT + s * MB + c0];
            w[s][3] = *(const float4*)&Ws[(k + 3) * MBT + s * MB + c0];
        }
#pragma unroll
        for (int r = 0; r < RT; r++) {
            float4 av = *(const float4*)&As[(r0 + r) * KP + k];
#pragma unroll
            for (int s = 0; s < CS; s++) {
                acc[s][r].x += av.x * w[s][0].x + av.y * w[s][1].x + av.z * w[s][2].x + av.w * w[s][3].x;
                acc[s][r].y += av.x * w[s][0].y + av.y * w[s][1].y + av.z * w[s][2].y + av.w * w[s][3].y;
                acc[s][r].z += av.x * w[s][0].z + av.y * w[s][1].z + av.z * w[s][2].z + av.w * w[s][3].z;
                acc[s][r].w += av.x * w[s][0].w + av.y * w[s][1].w + av.z * w[s][2].w + av.w * w[s][3].w;
            }
        }
    }
#pragma unroll
    for (int r = 0; r < RT; r++) {
        int row = base + r0 + r;
        if (row < N) {
            float dd = PRESCALE ? dinv[row] : 1.f;
#pragma unroll
            for (int s = 0; s < CS; s++) {
                float4 v = acc[s][r];
                float4 bv = *(const float4*)&bs[s * MB + c0];
                v.x = fmaxf(v.x + bv.x, 0.f) * dd;
                v.y = fmaxf(v.y + bv.y, 0.f) * dd;
                v.z = fmaxf(v.z + bv.z, 0.f) * dd;
                v.w = fmaxf(v.w + bv.w, 0.f) * dd;
                ushort4 u;
                u.x = f_to_bf(v.x); u.y = f_to_bf(v.y);
                u.z = f_to_bf(v.z); u.w = f_to_bf(v.w);
                *(ushort4*)&out[(size_t)row * MBT + s * MB + c0] = u;
            }
        }
    }
}

// --- register-tiled GEMM (L1 only: fp32 x in, prescaled bf16 out) -----------
template<int K, int M, int MB, int RT, bool BIAS_RELU, bool PRESCALE, bool INBF, bool OUTBF>
__global__ __launch_bounds__(256) void gemm_kernel(
        const void* __restrict__ Av, const float* __restrict__ W,
        const float* __restrict__ bias, const float* __restrict__ dinv,
        void* __restrict__ outv, int N) {
    constexpr int CG = MB / 4;
    constexpr int TM = (256 / CG) * RT;
    constexpr int KP = K + 4;
    constexpr int MSPLIT = M / MB;
    static_assert(TM == 64, "tile rows");
    __shared__ float As[TM * KP];
    __shared__ float Ws[K * MB];
    __shared__ float bs[MB];
    const int t = threadIdx.x;
    const int base = (blockIdx.x / MSPLIT) * TM;
    const int colb = (blockIdx.x % MSPLIT) * MB;
    const int rows_valid = min(TM, N - base);
    if (INBF) {
        constexpr int KD8 = K / 8;
        const unsigned short* A = (const unsigned short*)Av;
        for (int idx = t; idx < TM * KD8; idx += 256) {
            int row = idx / KD8, kc = idx % KD8;
            if (row < rows_valid) {
                ushort8v u = *(const ushort8v*)&A[(size_t)(base + row) * K + kc * 8];
                float4 lo = {bf_to_f(u[0]), bf_to_f(u[1]), bf_to_f(u[2]), bf_to_f(u[3])};
                float4 hi = {bf_to_f(u[4]), bf_to_f(u[5]), bf_to_f(u[6]), bf_to_f(u[7])};
                *(float4*)&As[row * KP + kc * 8] = lo;
                *(float4*)&As[row * KP + kc * 8 + 4] = hi;
            }
        }
    } else {
        constexpr int KD4 = K / 4;
        const float* A = (const float*)Av;
        for (int idx = t; idx < TM * KD4; idx += 256) {
            int row = idx / KD4, kc = idx % KD4;
            if (row < rows_valid)
                *(float4*)&As[row * KP + kc * 4] = *(const float4*)&A[(size_t)(base + row) * K + kc * 4];
        }
    }
    constexpr int MD4 = MB / 4;
    for (int idx = t; idx < K * MD4; idx += 256) {
        int k = idx / MD4, c4 = idx % MD4;
        *(float4*)&Ws[k * MB + c4 * 4] = *(const float4*)&W[(size_t)k * M + colb + c4 * 4];
    }
    if (BIAS_RELU && t < MB) bs[t] = bias[colb + t];
    __syncthreads();

    const int tc = t % CG;
    const int r0 = (t / CG) * RT;
    const int c0 = tc * 4;
    float4 acc[RT];
#pragma unroll
    for (int r = 0; r < RT; r++) acc[r] = {0.f, 0.f, 0.f, 0.f};

#pragma unroll 4
    for (int k = 0; k < K; k += 4) {
        float4 w0 = *(const float4*)&Ws[(k + 0) * MB + c0];
        float4 w1 = *(const float4*)&Ws[(k + 1) * MB + c0];
        float4 w2 = *(const float4*)&Ws[(k + 2) * MB + c0];
        float4 w3 = *(const float4*)&Ws[(k + 3) * MB + c0];
#pragma unroll
        for (int r = 0; r < RT; r++) {
            float4 av = *(const float4*)&As[(r0 + r) * KP + k];
            acc[r].x += av.x * w0.x + av.y * w1.x + av.z * w2.x + av.w * w3.x;
            acc[r].y += av.x * w0.y + av.y * w1.y + av.z * w2.y + av.w * w3.y;
            acc[r].z += av.x * w0.z + av.y * w1.z + av.z * w2.z + av.w * w3.z;
            acc[r].w += av.x * w0.w + av.y * w1.w + av.z * w2.w + av.w * w3.w;
        }
    }
#pragma unroll
    for (int r = 0; r < RT; r++) {
        int row = base + r0 + r;
        if (row < N) {
            float4 v = acc[r];
            if (BIAS_RELU) {
                float4 bv = *(const float4*)&bs[c0];
                v.x = fmaxf(v.x + bv.x, 0.f); v.y = fmaxf(v.y + bv.y, 0.f);
                v.z = fmaxf(v.z + bv.z, 0.f); v.w = fmaxf(v.w + bv.w, 0.f);
            }
            if (PRESCALE) {
                float d = dinv[row];
                v.x *= d; v.y *= d; v.z *= d; v.w *= d;
            }
            if (OUTBF) {
                ushort4 u;
                u.x = f_to_bf(v.x); u.y = f_to_bf(v.y);
                u.z = f_to_bf(v.z); u.w = f_to_bf(v.w);
                *(ushort4*)&((unsigned short*)outv)[(size_t)row * M + colb + c0] = u;
            } else {
                *(float4*)&((float*)outv)[(size_t)row * M + colb + c0] = v;
            }
        }
    }
}

// --- fused FC head: h5 = relu(h4 @ Wf1 + bf1); out = tanh(h5 @ Wf2 + bf2) ---
__global__ __launch_bounds__(256) void head_kernel(
        const unsigned short* __restrict__ A, const float* __restrict__ Wf1,
        const float* __restrict__ bf1, const float* __restrict__ Wf2,
        const float* __restrict__ bf2, float* __restrict__ out, int N) {
    constexpr int K = 128, MB = 32, RT = 2, CG = 8, TM = 64, KP = K + 4;
    __shared__ float As[TM * KP];        // reused as h5 tile after k-loop
    __shared__ float Ws[K * MB];
    __shared__ float bs[MB];
    __shared__ float wt2[10 * 32];       // Wf2 transposed: wt2[m*32+k]
    __shared__ float bs2[10];
    const int t = threadIdx.x;
    const int base = blockIdx.x * TM;
    const int rows_valid = min(TM, N - base);
    constexpr int KD8 = K / 8;
    for (int idx = t; idx < TM * KD8; idx += 256) {
        int row = idx / KD8, kc = idx % KD8;
        if (row < rows_valid) {
            ushort8v u = *(const ushort8v*)&A[(size_t)(base + row) * K + kc * 8];
            float4 lo = {bf_to_f(u[0]), bf_to_f(u[1]), bf_to_f(u[2]), bf_to_f(u[3])};
            float4 hi = {bf_to_f(u[4]), bf_to_f(u[5]), bf_to_f(u[6]), bf_to_f(u[7])};
            *(float4*)&As[row * KP + kc * 8] = lo;
            *(float4*)&As[row * KP + kc * 8 + 4] = hi;
        }
    }
    for (int idx = t; idx < K * MB / 4; idx += 256) {
        int k = idx / (MB / 4), c4 = idx % (MB / 4);
        *(float4*)&Ws[k * MB + c4 * 4] = *(const float4*)&Wf1[(size_t)k * MB + c4 * 4];
    }
    if (t < MB) bs[t] = bf1[t];
    for (int idx = t; idx < 320; idx += 256)                 // strided staging
        wt2[(idx % 10) * 32 + idx / 10] = Wf2[idx];
    if (t < 10) bs2[t] = bf2[t];
    __syncthreads();

    const int tc = t % CG;
    const int r0 = (t / CG) * RT;
    const int c0 = tc * 4;
    float4 acc[RT];
#pragma unroll
    for (int r = 0; r < RT; r++) acc[r] = {0.f, 0.f, 0.f, 0.f};
#pragma unroll 4
    for (int k = 0; k < K; k += 4) {
        float4 w0 = *(const float4*)&Ws[(k + 0) * MB + c0];
        float4 w1 = *(const float4*)&Ws[(k + 1) * MB + c0];
        float4 w2 = *(const float4*)&Ws[(k + 2) * MB + c0];
        float4 w3 = *(const float4*)&Ws[(k + 3) * MB + c0];
#pragma unroll
        for (int r = 0; r < RT; r++) {
            float4 av = *(const float4*)&As[(r0 + r) * KP + k];
            acc[r].x += av.x * w0.x + av.y * w1.x + av.z * w2.x + av.w * w3.x;
            acc[r].y += av.x * w0.y + av.y * w1.y + av.z * w2.y + av.w * w3.y;
            acc[r].z += av.x * w0.z + av.y * w1.z + av.z * w2.z + av.w * w3.z;
            acc[r].w += av.x * w0.w + av.y * w1.w + av.z * w2.w + av.w * w3.w;
        }
    }
    __syncthreads();                     // all As reads done -> safe to alias
    float* h5s = As;                     // 64 x 32 tile, stride 33
#pragma unroll
    for (int r = 0; r < RT; r++) {
        int row = r0 + r;
        float4 bv = *(const float4*)&bs[c0];
        h5s[row * 33 + c0 + 0] = fmaxf(acc[r].x + bv.x, 0.f);
        h5s[row * 33 + c0 + 1] = fmaxf(acc[r].y + bv.y, 0.f);
        h5s[row * 33 + c0 + 2] = fmaxf(acc[r].z + bv.z, 0.f);
        h5s[row * 33 + c0 + 3] = fmaxf(acc[r].w + bv.w, 0.f);
    }
    __syncthreads();
    const int lrow = t >> 2;             // 0..63
    const int q = t & 3;
    const int grow = base + lrow;
    if (grow < N) {
        for (int m = q; m < 10; m += 4) {
            float a = bs2[m];
#pragma unroll
            for (int k = 0; k < 32; k++) a += h5s[lrow * 33 + k] * wt2[m * 32 + k];
            out[(size_t)grow * 10 + m] = tanhf(a);
        }
    }
}

extern "C" void kernel_launch(void* const* d_in, const int* in_sizes, int n_in,
                              void* d_out, int out_size, void* d_ws, size_t ws_size,
                              hipStream_t stream) {
    const float* x   = (const float*)d_in[0];
    const int*   ei  = (const int*)d_in[1];     // int32 on device
    const float* W1  = (const float*)d_in[2];
    const float* b1  = (const float*)d_in[3];
    const float* W2  = (const float*)d_in[4];
    const float* b2  = (const float*)d_in[5];
    const float* W3  = (const float*)d_in[6];
    const float* b3  = (const float*)d_in[7];
    const float* W4  = (const float*)d_in[8];
    const float* b4  = (const float*)d_in[9];
    const float* Wf1 = (const float*)d_in[10];
    const float* bf1 = (const float*)d_in[11];
    const float* Wf2 = (const float*)d_in[12];
    const float* bf2 = (const float*)d_in[13];

    const int N = in_sizes[0] / 128;   // 100000
    const int E = in_sizes[1] / 2;     // 1600000
    const int* e_src = ei;
    const int* e_dst = ei + E;

    char* p = (char*)d_ws;
    auto carve = [&](size_t bytes) -> void* {
        void* r = (void*)p;
        p += (bytes + 255) & ~(size_t)255;
        return r;
    };
    int*   bucket_cur = (int*)carve(512 * 4);
    float* dinv       = (float*)carve((size_t)N * 4);
    int*   row_ptr    = (int*)carve((size_t)N * 4);
    int*   degp       = (int*)carve((size_t)N * 4);
    int*   csr_tmp    = (int*)carve((size_t)NBUCK * BCAP * 4);
    int*   csr_src    = (int*)carve((size_t)NBUCK * BCAP * 4);
    unsigned short* bufP = (unsigned short*)carve((size_t)N * 128 * 2); // bf16 ping
    unsigned short* bufQ = (unsigned short*)carve((size_t)N * 128 * 2); // bf16 pong

    const int GB   = (N + 63) / 64;    // 1563 row-blocks
    const int AG16 = (N + 127) / 128;  // F=16 agg: 128 nodes/block

    // --- graph preprocessing: cursor init, place, bsort(+deg+dinv) ---
    init_cursor_kernel<<<2, 256, 0, stream>>>(bucket_cur);
    place_kernel<<<PREB, 256, 0, stream>>>(e_src, e_dst, bucket_cur, csr_tmp, E);
    bsort_kernel<<<NBUCK, 256, 0, stream>>>(bucket_cur, csr_tmp, row_ptr, csr_src, degp, dinv, N);

    // --- L1 (128->16): prescaled GEMM -> bf16 z1; standalone agg (bias+relu)
    gemm_kernel<128, 16, 16, 1, false, true, false, true><<<GB, 256, 0, stream>>>(
        x, W1, nullptr, dinv, bufP, N);
    agg_gpn_kernel<16, true, true><<<AG16, 256, 0, stream>>>(
        bufP, row_ptr, degp, csr_src, dinv, b1, bufQ, N);

    // --- L2 (16->32): fused agg+GEMM -> bf16 z2 (prescaled) ---
    gemm_agg_kernel<16, 32, 2, 1, 4, true><<<GB, 256, 0, stream>>>(
        bufQ, row_ptr, degp, csr_src, dinv, W2, b2, bufP, N);

    // --- L3 (32->64): fused agg+GEMM -> bf16 z3 (prescaled) ---
    gemm_agg_kernel<32, 64, 4, 1, 8, true><<<GB, 256, 0, stream>>>(
        bufP, row_ptr, degp, csr_src, dinv, W3, b3, bufQ, N);

    // --- L4 (64->128): fused agg+GEMM, CS=2 full-width -> bf16 h4 ---
    gemm_agg_kernel<64, 64, 4, 2, 8, false><<<GB, 256, 0, stream>>>(
        bufQ, row_ptr, degp, csr_src, dinv, W4, b4, bufP, N);

    // --- fused FC head: relu(h4 Wf1 + bf1) -> tanh(. Wf2 + bf2) ---
    head_kernel<<<GB, 256, 0, stream>>>(bufP, Wf1, bf1, Wf2, bf2, (float*)d_out, N);
}

// Round 4
// 319.909 us; speedup vs baseline: 4.4865x; 1.0704x over previous
//
#include <hip/hip_runtime.h>
#include <hip/hip_bf16.h>
#include <cmath>

// ---------------------------------------------------------------------------
// GCN: out = tanh(relu(relu(relu(relu(P(P(P(P(xW1+..)..) .. ))Wf1+bf1)Wf2+bf2
// P = D^-1/2 (A+I) D^-1/2 via bucketed CSR gather-sum, no float atomics.
// R14: group-per-node register agg (345.7us). R15: fixed-cap buckets (hist+
// scan deleted) + agg fused into GEMM A-staging, 9 dispatches (342.4us) --
// BUT fused L4 regressed to 75us: Ws(32K)+As(17.4K) LDS -> 3 blocks/CU ->
// occupancy 23.6%, starving the latency-bound gather phase of waves.
// R16: (a) L4 reads W4 from GLOBAL in the GEMM inner loop (32KB, L1/L2-
// resident, uniform across blocks) -> LDS 50.7K->17.9K -> ~7 blocks/CU;
// (b) U=8 gather main loop in fused kernels (8 gathers in flight per lane,
// ~2x MLP) since gather is latency- not BW-bound (hbm 18%, VALU 33%).
// ---------------------------------------------------------------------------

#define NBUCK 391              // ceil(100000/256) 256-node buckets
#define PREB  391              // ceil(E/4096) edge-phase blocks
#define BCAP  5120             // edges per bucket capacity (mean 4096, 16s)

typedef __attribute__((ext_vector_type(8))) unsigned short ushort8v;

__device__ __forceinline__ unsigned short f_to_bf(float v) {
    unsigned u = __float_as_uint(v);
    return (unsigned short)((u + 0x7FFF + ((u >> 16) & 1)) >> 16);   // RTN-even
}
__device__ __forceinline__ float bf_to_f(unsigned short v) {
    return __uint_as_float((unsigned)v << 16);
}

template<int VE> struct BFV;
template<> struct BFV<4> {
    using T = ushort4;
    __device__ static inline void unpack(const T& u, float* f) {
        f[0] = bf_to_f(u.x); f[1] = bf_to_f(u.y);
        f[2] = bf_to_f(u.z); f[3] = bf_to_f(u.w);
    }
};
template<> struct BFV<8> {
    using T = ushort8v;
    __device__ static inline void unpack(const T& u, float* f) {
#pragma unroll
        for (int j = 0; j < 8; j++) f[j] = bf_to_f(u[j]);
    }
};

__device__ __forceinline__ ushort8v pack8(const float* f) {
    ushort8v u;
#pragma unroll
    for (int j = 0; j < 8; j++) u[j] = f_to_bf(f[j]);
    return u;
}

__global__ void init_cursor_kernel(int* __restrict__ cur) {
    int i = blockIdx.x * 256 + threadIdx.x;
    if (i < NBUCK) cur[i] = i * BCAP;
}

// Phase A: scatter packed edges into fixed-capacity bucket regions.
// payload = (dst&255)<<17 | src. cursors pre-init'ed to b*BCAP.
__global__ __launch_bounds__(256) void place_kernel(
        const int* __restrict__ src, const int* __restrict__ dst,
        int* __restrict__ bucket_cursor, int* __restrict__ csr_tmp, int E) {
    __shared__ int hist[NBUCK];
    const int t = threadIdx.x;
    for (int i = t; i < NBUCK; i += 256) hist[i] = 0;
    __syncthreads();
    const int base = blockIdx.x * 4096;
    int pay[16], rb[16];
#pragma unroll
    for (int j = 0; j < 16; j++) {
        int e = base + j * 256 + t;
        if (e < E) {
            int d = dst[e];
            int b = d >> 8;
            int r = atomicAdd(&hist[b], 1);       // r < 4096 (12 bits)
            pay[j] = ((d & 255) << 17) | src[e];
            rb[j] = (r << 9) | b;                 // b < 512 (9 bits)
        } else rb[j] = -1;
    }
    __syncthreads();
    for (int i = t; i < NBUCK; i += 256) {
        int h = hist[i];
        hist[i] = h ? atomicAdd(&bucket_cursor[i], h) : 0;
    }
    __syncthreads();
#pragma unroll
    for (int j = 0; j < 16; j++) {
        if (rb[j] >= 0) {
            int b = rb[j] & 511;
            int r = rb[j] >> 9;
            csr_tmp[hist[b] + r] = pay[j];
        }
    }
}

// Phase B: one block per bucket -> per-node CSR (row_ptr + deg + csr_src,
// padded-bucket layout) + dinv.
__global__ __launch_bounds__(256) void bsort_kernel(
        const int* __restrict__ bucket_cursor, const int* __restrict__ csr_tmp,
        int* __restrict__ row_ptr, int* __restrict__ csr_src,
        int* __restrict__ degp, float* __restrict__ dinv, int N) {
    __shared__ int c[256], s[256], cur[256];
    const int b = blockIdx.x;
    const int t = threadIdx.x;
    const int start = b * BCAP;
    const int end = bucket_cursor[b];            // absolute fill end
    c[t] = 0;
    __syncthreads();
    for (int e = start + t; e < end; e += 256)
        atomicAdd(&c[csr_tmp[e] >> 17], 1);
    __syncthreads();
    int v = c[t];
    s[t] = v; __syncthreads();
    for (int off = 1; off < 256; off <<= 1) {
        int x = (t >= off) ? s[t - off] : 0;
        __syncthreads();
        s[t] += x;
        __syncthreads();
    }
    int excl = s[t] - v;
    int node = (b << 8) + t;
    if (node < N) {
        row_ptr[node] = start + excl;
        degp[node] = v;
        dinv[node] = rsqrtf((float)v + 1.0f);
    }
    cur[t] = start + excl;
    __syncthreads();
    for (int e = start + t; e < end; e += 256) {
        int p = csr_tmp[e];
        int pos = atomicAdd(&cur[p >> 17], 1);
        csr_src[pos] = p & 0x1FFFF;
    }
}

// --- group-per-node bf16 aggregation over PRESCALED input zs = dinv*z ------
// Used standalone only for L1 (bias+relu, prescale-out). G = F/8 lanes own
// one node; 8 channels/lane in registers, U=4 gathers in flight.
template<int F, bool L1MODE, bool PRESCALE_OUT>
__global__ __launch_bounds__(256) void agg_gpn_kernel(
        const unsigned short* __restrict__ z, const int* __restrict__ row_ptr,
        const int* __restrict__ degp, const int* __restrict__ csr_src,
        const float* __restrict__ dinv, const float* __restrict__ bias,
        unsigned short* __restrict__ out, int N) {
    constexpr int G  = F / 8;          // lanes per node
    constexpr int NPB = 256 / G;       // nodes per block
    const int t = threadIdx.x;
    const int c0 = (t % G) * 8;
    const int node = blockIdx.x * NPB + t / G;
    if (node >= N) return;             // group-uniform exit, no barriers below
    const int start = row_ptr[node];
    const int end   = start + degp[node];
    float acc[8];
#pragma unroll
    for (int j = 0; j < 8; j++) acc[j] = 0.f;
    int e = start;
    while (e + 3 < end) {              // U=4: 4 independent gathers in flight
        int s0 = csr_src[e];
        int s1 = csr_src[e + 1];
        int s2 = csr_src[e + 2];
        int s3 = csr_src[e + 3];
        ushort8v u0 = *(const ushort8v*)&z[(size_t)s0 * F + c0];
        ushort8v u1 = *(const ushort8v*)&z[(size_t)s1 * F + c0];
        ushort8v u2 = *(const ushort8v*)&z[(size_t)s2 * F + c0];
        ushort8v u3 = *(const ushort8v*)&z[(size_t)s3 * F + c0];
        float f0[8], f1[8], f2[8], f3[8];
        BFV<8>::unpack(u0, f0); BFV<8>::unpack(u1, f1);
        BFV<8>::unpack(u2, f2); BFV<8>::unpack(u3, f3);
#pragma unroll
        for (int j = 0; j < 8; j++) acc[j] += (f0[j] + f1[j]) + (f2[j] + f3[j]);
        e += 4;
    }
    if (e + 1 < end) {                 // U=2
        int s0 = csr_src[e];
        int s1 = csr_src[e + 1];
        ushort8v u0 = *(const ushort8v*)&z[(size_t)s0 * F + c0];
        ushort8v u1 = *(const ushort8v*)&z[(size_t)s1 * F + c0];
        float f0[8], f1[8];
        BFV<8>::unpack(u0, f0); BFV<8>::unpack(u1, f1);
#pragma unroll
        for (int j = 0; j < 8; j++) acc[j] += f0[j] + f1[j];
        e += 2;
    }
    if (e < end) {                     // tail
        int s0 = csr_src[e];
        ushort8v u0 = *(const ushort8v*)&z[(size_t)s0 * F + c0];
        float f0[8];
        BFV<8>::unpack(u0, f0);
#pragma unroll
        for (int j = 0; j < 8; j++) acc[j] += f0[j];
    }
    const float di = dinv[node];
    ushort8v us = *(const ushort8v*)&z[(size_t)node * F + c0];
    float fs[8], r[8];
    BFV<8>::unpack(us, fs);
#pragma unroll
    for (int j = 0; j < 8; j++) r[j] = di * (acc[j] + fs[j]);
    if (L1MODE) {
#pragma unroll
        for (int j = 0; j < 8; j++) r[j] = fmaxf(r[j] + bias[c0 + j], 0.f);
    }
    if (PRESCALE_OUT) {
#pragma unroll
        for (int j = 0; j < 8; j++) r[j] *= di;
    }
    *(ushort8v*)&out[(size_t)node * F + c0] = pack8(r);
}

// --- fused agg+GEMM: As[r][k] = dinv*(sum_e z[src][k] + z[r][k]); then
// out = relu(As @ W + b) [* dinv if PRESCALE], bf16 out, width MB*CS.
// CPL channels per lane during gather; CS col-splits in-register (one
// gather covers the full output width). WLDS=false: skip Ws LDS staging,
// read W from global (L1/L2-resident) -> small LDS -> high occupancy for
// the latency-bound gather phase. U = gathers in flight per lane.
template<int K, int MB, int RT, int CS, int CPL, bool PRESCALE, bool WLDS, int U>
__global__ __launch_bounds__(256) void gemm_agg_kernel(
        const unsigned short* __restrict__ z, const int* __restrict__ row_ptr,
        const int* __restrict__ degp, const int* __restrict__ csr_src,
        const float* __restrict__ dinv, const float* __restrict__ W,
        const float* __restrict__ bias, unsigned short* __restrict__ out, int N) {
    constexpr int CG = MB / 4;
    constexpr int TM = (256 / CG) * RT;
    constexpr int KP = K + 4;            // 2-way bank alias on As reads (free)
    constexpr int MBT = MB * CS;
    static_assert(TM == 64, "tile rows");
    __shared__ float As[TM * KP];
    __shared__ float Ws[WLDS ? K * MBT : 4];
    __shared__ float bs[MBT];
    const int t = threadIdx.x;
    const int base = blockIdx.x * TM;

    {   // ---- gather-staged A (the fused aggregation) ----
        using VT = typename BFV<CPL>::T;
        constexpr int G = K / CPL;       // lanes per node
        constexpr int NPB = 256 / G;     // nodes in flight
        const int gg = t / G;
        const int ac0 = (t % G) * CPL;
        for (int r = gg; r < TM; r += NPB) {
            const int node = base + r;
            float res[CPL];
            if (node < N) {
                const int start = row_ptr[node];
                const int end = start + degp[node];
                float acc[CPL];
#pragma unroll
                for (int j = 0; j < CPL; j++) acc[j] = 0.f;
                int e = start;
                if (U == 8) {
                    while (e + 7 < end) {    // U=8 gathers in flight
                        int ss[8];
#pragma unroll
                        for (int u = 0; u < 8; u++) ss[u] = csr_src[e + u];
                        VT uu[8];
#pragma unroll
                        for (int u = 0; u < 8; u++)
                            uu[u] = *(const VT*)&z[(size_t)ss[u] * K + ac0];
#pragma unroll
                        for (int u = 0; u < 8; u++) {
                            float f[CPL];
                            BFV<CPL>::unpack(uu[u], f);
#pragma unroll
                            for (int j = 0; j < CPL; j++) acc[j] += f[j];
                        }
                        e += 8;
                    }
                }
                while (e + 3 < end) {    // U=4 gathers in flight
                    int s0 = csr_src[e];
                    int s1 = csr_src[e + 1];
                    int s2 = csr_src[e + 2];
                    int s3 = csr_src[e + 3];
                    VT u0 = *(const VT*)&z[(size_t)s0 * K + ac0];
                    VT u1 = *(const VT*)&z[(size_t)s1 * K + ac0];
                    VT u2 = *(const VT*)&z[(size_t)s2 * K + ac0];
                    VT u3 = *(const VT*)&z[(size_t)s3 * K + ac0];
                    float f0[CPL], f1[CPL], f2[CPL], f3[CPL];
                    BFV<CPL>::unpack(u0, f0); BFV<CPL>::unpack(u1, f1);
                    BFV<CPL>::unpack(u2, f2); BFV<CPL>::unpack(u3, f3);
#pragma unroll
                    for (int j = 0; j < CPL; j++)
                        acc[j] += (f0[j] + f1[j]) + (f2[j] + f3[j]);
                    e += 4;
                }
                if (e + 1 < end) {       // U=2
                    int s0 = csr_src[e];
                    int s1 = csr_src[e + 1];
                    VT u0 = *(const VT*)&z[(size_t)s0 * K + ac0];
                    VT u1 = *(const VT*)&z[(size_t)s1 * K + ac0];
                    float f0[CPL], f1[CPL];
                    BFV<CPL>::unpack(u0, f0); BFV<CPL>::unpack(u1, f1);
#pragma unroll
                    for (int j = 0; j < CPL; j++) acc[j] += f0[j] + f1[j];
                    e += 2;
                }
                if (e < end) {           // tail
                    int s0 = csr_src[e];
                    VT u0 = *(const VT*)&z[(size_t)s0 * K + ac0];
                    float f0[CPL];
                    BFV<CPL>::unpack(u0, f0);
#pragma unroll
                    for (int j = 0; j < CPL; j++) acc[j] += f0[j];
                }
                const float di = dinv[node];
                VT us = *(const VT*)&z[(size_t)node * K + ac0];
                float fs[CPL];
                BFV<CPL>::unpack(us, fs);
#pragma unroll
                for (int j = 0; j < CPL; j++) res[j] = di * (acc[j] + fs[j]);
            } else {
#pragma unroll
                for (int j = 0; j < CPL; j++) res[j] = 0.f;
            }
#pragma unroll
            for (int j = 0; j < CPL; j++) As[r * KP + ac0 + j] = res[j];
        }
    }
    // ---- W (optional) + bias staging ----
    if (WLDS) {
        constexpr int MD4 = MBT / 4;
        for (int idx = t; idx < K * MD4; idx += 256) {
            int k = idx / MD4, c4 = idx % MD4;
            *(float4*)&Ws[k * MBT + c4 * 4] = *(const float4*)&W[(size_t)k * MBT + c4 * 4];
        }
    }
    if (t < MBT) bs[t] = bias[t];
    __syncthreads();

    const int tc = t % CG;
    const int r0 = (t / CG) * RT;
    const int c0 = tc * 4;
    float4 acc[CS][RT];
#pragma unroll
    for (int s = 0; s < CS; s++)
#pragma unroll
        for (int r = 0; r < RT; r++) acc[s][r] = {0.f, 0.f, 0.f, 0.f};

#pragma unroll 4
    for (int k = 0; k < K; k += 4) {
        float4 w[CS][4];
#pragma unroll
        for (int s = 0; s < CS; s++) {
#pragma unroll
            for (int i = 0; i < 4; i++) {
                if (WLDS)
                    w[s][i] = *(const float4*)&Ws[(k + i) * MBT + s * MB + c0];
                else
                    w[s][i] = *(const float4*)&W[(size_t)(k + i) * MBT + s * MB + c0];
            }
        }
#pragma unroll
        for (int r = 0; r < RT; r++) {
            float4 av = *(const float4*)&As[(r0 + r) * KP + k];
#pragma unroll
            for (int s = 0; s < CS; s++) {
                acc[s][r].x += av.x * w[s][0].x + av.y * w[s][1].x + av.z * w[s][2].x + av.w * w[s][3].x;
                acc[s][r].y += av.x * w[s][0].y + av.y * w[s][1].y + av.z * w[s][2].y + av.w * w[s][3].y;
                acc[s][r].z += av.x * w[s][0].z + av.y * w[s][1].z + av.z * w[s][2].z + av.w * w[s][3].z;
                acc[s][r].w += av.x * w[s][0].w + av.y * w[s][1].w + av.z * w[s][2].w + av.w * w[s][3].w;
            }
        }
    }
#pragma unroll
    for (int r = 0; r < RT; r++) {
        int row = base + r0 + r;
        if (row < N) {
            float dd = PRESCALE ? dinv[row] : 1.f;
#pragma unroll
            for (int s = 0; s < CS; s++) {
                float4 v = acc[s][r];
                float4 bv = *(const float4*)&bs[s * MB + c0];
                v.x = fmaxf(v.x + bv.x, 0.f) * dd;
                v.y = fmaxf(v.y + bv.y, 0.f) * dd;
                v.z = fmaxf(v.z + bv.z, 0.f) * dd;
                v.w = fmaxf(v.w + bv.w, 0.f) * dd;
                ushort4 u;
                u.x = f_to_bf(v.x); u.y = f_to_bf(v.y);
                u.z = f_to_bf(v.z); u.w = f_to_bf(v.w);
                *(ushort4*)&out[(size_t)row * MBT + s * MB + c0] = u;
            }
        }
    }
}

// --- register-tiled GEMM (L1 only: fp32 x in, prescaled bf16 out) -----------
template<int K, int M, int MB, int RT, bool BIAS_RELU, bool PRESCALE, bool INBF, bool OUTBF>
__global__ __launch_bounds__(256) void gemm_kernel(
        const void* __restrict__ Av, const float* __restrict__ W,
        const float* __restrict__ bias, const float* __restrict__ dinv,
        void* __restrict__ outv, int N) {
    constexpr int CG = MB / 4;
    constexpr int TM = (256 / CG) * RT;
    constexpr int KP = K + 4;
    constexpr int MSPLIT = M / MB;
    static_assert(TM == 64, "tile rows");
    __shared__ float As[TM * KP];
    __shared__ float Ws[K * MB];
    __shared__ float bs[MB];
    const int t = threadIdx.x;
    const int base = (blockIdx.x / MSPLIT) * TM;
    const int colb = (blockIdx.x % MSPLIT) * MB;
    const int rows_valid = min(TM, N - base);
    if (INBF) {
        constexpr int KD8 = K / 8;
        const unsigned short* A = (const unsigned short*)Av;
        for (int idx = t; idx < TM * KD8; idx += 256) {
            int row = idx / KD8, kc = idx % KD8;
            if (row < rows_valid) {
                ushort8v u = *(const ushort8v*)&A[(size_t)(base + row) * K + kc * 8];
                float4 lo = {bf_to_f(u[0]), bf_to_f(u[1]), bf_to_f(u[2]), bf_to_f(u[3])};
                float4 hi = {bf_to_f(u[4]), bf_to_f(u[5]), bf_to_f(u[6]), bf_to_f(u[7])};
                *(float4*)&As[row * KP + kc * 8] = lo;
                *(float4*)&As[row * KP + kc * 8 + 4] = hi;
            }
        }
    } else {
        constexpr int KD4 = K / 4;
        const float* A = (const float*)Av;
        for (int idx = t; idx < TM * KD4; idx += 256) {
            int row = idx / KD4, kc = idx % KD4;
            if (row < rows_valid)
                *(float4*)&As[row * KP + kc * 4] = *(const float4*)&A[(size_t)(base + row) * K + kc * 4];
        }
    }
    constexpr int MD4 = MB / 4;
    for (int idx = t; idx < K * MD4; idx += 256) {
        int k = idx / MD4, c4 = idx % MD4;
        *(float4*)&Ws[k * MB + c4 * 4] = *(const float4*)&W[(size_t)k * M + colb + c4 * 4];
    }
    if (BIAS_RELU && t < MB) bs[t] = bias[colb + t];
    __syncthreads();

    const int tc = t % CG;
    const int r0 = (t / CG) * RT;
    const int c0 = tc * 4;
    float4 acc[RT];
#pragma unroll
    for (int r = 0; r < RT; r++) acc[r] = {0.f, 0.f, 0.f, 0.f};

#pragma unroll 4
    for (int k = 0; k < K; k += 4) {
        float4 w0 = *(const float4*)&Ws[(k + 0) * MB + c0];
        float4 w1 = *(const float4*)&Ws[(k + 1) * MB + c0];
        float4 w2 = *(const float4*)&Ws[(k + 2) * MB + c0];
        float4 w3 = *(const float4*)&Ws[(k + 3) * MB + c0];
#pragma unroll
        for (int r = 0; r < RT; r++) {
            float4 av = *(const float4*)&As[(r0 + r) * KP + k];
            acc[r].x += av.x * w0.x + av.y * w1.x + av.z * w2.x + av.w * w3.x;
            acc[r].y += av.x * w0.y + av.y * w1.y + av.z * w2.y + av.w * w3.y;
            acc[r].z += av.x * w0.z + av.y * w1.z + av.z * w2.z + av.w * w3.z;
            acc[r].w += av.x * w0.w + av.y * w1.w + av.z * w2.w + av.w * w3.w;
        }
    }
#pragma unroll
    for (int r = 0; r < RT; r++) {
        int row = base + r0 + r;
        if (row < N) {
            float4 v = acc[r];
            if (BIAS_RELU) {
                float4 bv = *(const float4*)&bs[c0];
                v.x = fmaxf(v.x + bv.x, 0.f); v.y = fmaxf(v.y + bv.y, 0.f);
                v.z = fmaxf(v.z + bv.z, 0.f); v.w = fmaxf(v.w + bv.w, 0.f);
            }
            if (PRESCALE) {
                float d = dinv[row];
                v.x *= d; v.y *= d; v.z *= d; v.w *= d;
            }
            if (OUTBF) {
                ushort4 u;
                u.x = f_to_bf(v.x); u.y = f_to_bf(v.y);
                u.z = f_to_bf(v.z); u.w = f_to_bf(v.w);
                *(ushort4*)&((unsigned short*)outv)[(size_t)row * M + colb + c0] = u;
            } else {
                *(float4*)&((float*)outv)[(size_t)row * M + colb + c0] = v;
            }
        }
    }
}

// --- fused FC head: h5 = relu(h4 @ Wf1 + bf1); out = tanh(h5 @ Wf2 + bf2) ---
__global__ __launch_bounds__(256) void head_kernel(
        const unsigned short* __restrict__ A, const float* __restrict__ Wf1,
        const float* __restrict__ bf1, const float* __restrict__ Wf2,
        const float* __restrict__ bf2, float* __restrict__ out, int N) {
    constexpr int K = 128, MB = 32, RT = 2, CG = 8, TM = 64, KP = K + 4;
    __shared__ float As[TM * KP];        // reused as h5 tile after k-loop
    __shared__ float Ws[K * MB];
    __shared__ float bs[MB];
    __shared__ float wt2[10 * 32];       // Wf2 transposed: wt2[m*32+k]
    __shared__ float bs2[10];
    const int t = threadIdx.x;
    const int base = blockIdx.x * TM;
    const int rows_valid = min(TM, N - base);
    constexpr int KD8 = K / 8;
    for (int idx = t; idx < TM * KD8; idx += 256) {
        int row = idx / KD8, kc = idx % KD8;
        if (row < rows_valid) {
            ushort8v u = *(const ushort8v*)&A[(size_t)(base + row) * K + kc * 8];
            float4 lo = {bf_to_f(u[0]), bf_to_f(u[1]), bf_to_f(u[2]), bf_to_f(u[3])};
            float4 hi = {bf_to_f(u[4]), bf_to_f(u[5]), bf_to_f(u[6]), bf_to_f(u[7])};
            *(float4*)&As[row * KP + kc * 8] = lo;
            *(float4*)&As[row * KP + kc * 8 + 4] = hi;
        }
    }
    for (int idx = t; idx < K * MB / 4; idx += 256) {
        int k = idx / (MB / 4), c4 = idx % (MB / 4);
        *(float4*)&Ws[k * MB + c4 * 4] = *(const float4*)&Wf1[(size_t)k * MB + c4 * 4];
    }
    if (t < MB) bs[t] = bf1[t];
    for (int idx = t; idx < 320; idx += 256)                 // strided staging
        wt2[(idx % 10) * 32 + idx / 10] = Wf2[idx];
    if (t < 10) bs2[t] = bf2[t];
    __syncthreads();

    const int tc = t % CG;
    const int r0 = (t / CG) * RT;
    const int c0 = tc * 4;
    float4 acc[RT];
#pragma unroll
    for (int r = 0; r < RT; r++) acc[r] = {0.f, 0.f, 0.f, 0.f};
#pragma unroll 4
    for (int k = 0; k < K; k += 4) {
        float4 w0 = *(const float4*)&Ws[(k + 0) * MB + c0];
        float4 w1 = *(const float4*)&Ws[(k + 1) * MB + c0];
        float4 w2 = *(const float4*)&Ws[(k + 2) * MB + c0];
        float4 w3 = *(const float4*)&Ws[(k + 3) * MB + c0];
#pragma unroll
        for (int r = 0; r < RT; r++) {
            float4 av = *(const float4*)&As[(r0 + r) * KP + k];
            acc[r].x += av.x * w0.x + av.y * w1.x + av.z * w2.x + av.w * w3.x;
            acc[r].y += av.x * w0.y + av.y * w1.y + av.z * w2.y + av.w * w3.y;
            acc[r].z += av.x * w0.z + av.y * w1.z + av.z * w2.z + av.w * w3.z;
            acc[r].w += av.x * w0.w + av.y * w1.w + av.z * w2.w + av.w * w3.w;
        }
    }
    __syncthreads();                     // all As reads done -> safe to alias
    float* h5s = As;                     // 64 x 32 tile, stride 33
#pragma unroll
    for (int r = 0; r < RT; r++) {
        int row = r0 + r;
        float4 bv = *(const float4*)&bs[c0];
        h5s[row * 33 + c0 + 0] = fmaxf(acc[r].x + bv.x, 0.f);
        h5s[row * 33 + c0 + 1] = fmaxf(acc[r].y + bv.y, 0.f);
        h5s[row * 33 + c0 + 2] = fmaxf(acc[r].z + bv.z, 0.f);
        h5s[row * 33 + c0 + 3] = fmaxf(acc[r].w + bv.w, 0.f);
    }
    __syncthreads();
    const int lrow = t >> 2;             // 0..63
    const int q = t & 3;
    const int grow = base + lrow;
    if (grow < N) {
        for (int m = q; m < 10; m += 4) {
            float a = bs2[m];
#pragma unroll
            for (int k = 0; k < 32; k++) a += h5s[lrow * 33 + k] * wt2[m * 32 + k];
            out[(size_t)grow * 10 + m] = tanhf(a);
        }
    }
}

extern "C" void kernel_launch(void* const* d_in, const int* in_sizes, int n_in,
                              void* d_out, int out_size, void* d_ws, size_t ws_size,
                              hipStream_t stream) {
    const float* x   = (const float*)d_in[0];
    const int*   ei  = (const int*)d_in[1];     // int32 on device
    const float* W1  = (const float*)d_in[2];
    const float* b1  = (const float*)d_in[3];
    const float* W2  = (const float*)d_in[4];
    const float* b2  = (const float*)d_in[5];
    const float* W3  = (const float*)d_in[6];
    const float* b3  = (const float*)d_in[7];
    const float* W4  = (const float*)d_in[8];
    const float* b4  = (const float*)d_in[9];
    const float* Wf1 = (const float*)d_in[10];
    const float* bf1 = (const float*)d_in[11];
    const float* Wf2 = (const float*)d_in[12];
    const float* bf2 = (const float*)d_in[13];

    const int N = in_sizes[0] / 128;   // 100000
    const int E = in_sizes[1] / 2;     // 1600000
    const int* e_src = ei;
    const int* e_dst = ei + E;

    char* p = (char*)d_ws;
    auto carve = [&](size_t bytes) -> void* {
        void* r = (void*)p;
        p += (bytes + 255) & ~(size_t)255;
        return r;
    };
    int*   bucket_cur = (int*)carve(512 * 4);
    float* dinv       = (float*)carve((size_t)N * 4);
    int*   row_ptr    = (int*)carve((size_t)N * 4);
    int*   degp       = (int*)carve((size_t)N * 4);
    int*   csr_tmp    = (int*)carve((size_t)NBUCK * BCAP * 4);
    int*   csr_src    = (int*)carve((size_t)NBUCK * BCAP * 4);
    unsigned short* bufP = (unsigned short*)carve((size_t)N * 128 * 2); // bf16 ping
    unsigned short* bufQ = (unsigned short*)carve((size_t)N * 128 * 2); // bf16 pong

    const int GB   = (N + 63) / 64;    // 1563 row-blocks
    const int AG16 = (N + 127) / 128;  // F=16 agg: 128 nodes/block

    // --- graph preprocessing: cursor init, place, bsort(+deg+dinv) ---
    init_cursor_kernel<<<2, 256, 0, stream>>>(bucket_cur);
    place_kernel<<<PREB, 256, 0, stream>>>(e_src, e_dst, bucket_cur, csr_tmp, E);
    bsort_kernel<<<NBUCK, 256, 0, stream>>>(bucket_cur, csr_tmp, row_ptr, csr_src, degp, dinv, N);

    // --- L1 (128->16): prescaled GEMM -> bf16 z1; standalone agg (bias+relu)
    gemm_kernel<128, 16, 16, 1, false, true, false, true><<<GB, 256, 0, stream>>>(
        x, W1, nullptr, dinv, bufP, N);
    agg_gpn_kernel<16, true, true><<<AG16, 256, 0, stream>>>(
        bufP, row_ptr, degp, csr_src, dinv, b1, bufQ, N);

    // --- L2 (16->32): fused agg+GEMM -> bf16 z2 (prescaled) ---
    gemm_agg_kernel<16, 32, 2, 1, 4, true, true, 8><<<GB, 256, 0, stream>>>(
        bufQ, row_ptr, degp, csr_src, dinv, W2, b2, bufP, N);

    // --- L3 (32->64): fused agg+GEMM -> bf16 z3 (prescaled) ---
    gemm_agg_kernel<32, 64, 4, 1, 8, true, true, 8><<<GB, 256, 0, stream>>>(
        bufP, W3 ? row_ptr : row_ptr, degp, csr_src, dinv, W3, b3, bufQ, N);

    // --- L4 (64->128): fused agg+GEMM, CS=2, W from global (small LDS) ---
    gemm_agg_kernel<64, 64, 4, 2, 8, false, false, 8><<<GB, 256, 0, stream>>>(
        bufQ, row_ptr, degp, csr_src, dinv, W4, b4, bufP, N);

    // --- fused FC head: relu(h4 Wf1 + bf1) -> tanh(. Wf2 + bf2) ---
    head_kernel<<<GB, 256, 0, stream>>>(bufP, Wf1, bf1, Wf2, bf2, (float*)d_out, N);
}